// Round 15
// baseline (9792.954 us; speedup 1.0000x reference)
//
#include <hip/hip_runtime.h>
#include <hip/hip_bf16.h>

#define Bq 64
#define Tq 512
#define Eq 128
#define Hq 256
#define NTAGS 50
#define Mq (Bq*Tq)   // 32768

typedef _Float16 half2_t __attribute__((ext_vector_type(2)));

__device__ __forceinline__ float sigmoidf_(float x) { return 1.f / (1.f + __expf(-x)); }
__device__ __forceinline__ float tanhf_(float x) {
    float e = __expf(2.f * x);
    return 1.f - 2.f / (e + 1.f);
}

#if __has_builtin(__builtin_amdgcn_fdot2)
__device__ __forceinline__ float dot2_(unsigned w, unsigned h, float acc) {
    return __builtin_amdgcn_fdot2(__builtin_bit_cast(half2_t, w),
                                  __builtin_bit_cast(half2_t, h), acc, false);
}
#else
__device__ __forceinline__ float dot2_(unsigned w, unsigned h, float acc) {
    half2_t wv = __builtin_bit_cast(half2_t, w);
    half2_t hv = __builtin_bit_cast(half2_t, h);
    return acc + (float)wv.x * (float)hv.x + (float)wv.y * (float)hv.y;
}
#endif

// ---------------- dtype detection: int32 vs int64 for words/lengths ----------------
__global__ void detect_int64(const unsigned* __restrict__ words,
                             const unsigned* __restrict__ lens,
                             unsigned* __restrict__ dflags) {
    __shared__ int wbad, lbad, wnz, lnz;
    if (threadIdx.x == 0) { wbad = 0; lbad = 0; wnz = 0; lnz = 0; }
    __syncthreads();
    for (int i = threadIdx.x; i < 16384; i += blockDim.x) {
        if (words[2 * i + 1] != 0u) wbad = 1;
        if (words[2 * i] != 0u) wnz = 1;
    }
    for (int i = threadIdx.x; i < 32; i += blockDim.x) {
        if (lens[2 * i + 1] != 0u) lbad = 1;
        if (lens[2 * i] != 0u) lnz = 1;
    }
    __syncthreads();
    if (threadIdx.x == 0) {
        unsigned f = 0;
        if (!wbad && wnz) f |= 1u;
        if (!lbad && lnz) f |= 2u;
        dflags[0] = f;
    }
}

// ---------------- bias: bias[l][d][n] = bih + bhh ----------------
__global__ void bias_kernel(const float* b1f_ih, const float* b1f_hh,
                            const float* b1b_ih, const float* b1b_hh,
                            const float* b2f_ih, const float* b2f_hh,
                            const float* b2b_ih, const float* b2b_hh,
                            float* bias) {   // [4][1024]: l1f,l1b,l2f,l2b
    int i = blockIdx.x * blockDim.x + threadIdx.x;
    if (i >= 4096) return;
    int l = i >> 11, d = (i >> 10) & 1, nn = i & 1023;
    float v;
    if (l == 0) v = d ? (b1b_ih[nn] + b1b_hh[nn]) : (b1f_ih[nn] + b1f_hh[nn]);
    else        v = d ? (b2b_ih[nn] + b2b_hh[nn]) : (b2f_ih[nn] + b2f_hh[nn]);
    bias[i] = v;
}

// ---------------- Whh f16 two-plane packing ----------------
// plane_if[(k4*256+j)*8 + g01*4 + kk] : gates 0,1 ; plane_go : gates 2,3.
// Each (k4,j) chunk is 16B per plane -> wave loads are 1KB contiguous.
__global__ void pack_whh16(const float* __restrict__ W,
                           unsigned short* __restrict__ Pif,
                           unsigned short* __restrict__ Pgo) {
    int t = blockIdx.x * 256 + threadIdx.x;   // 0..65535
    if (t >= 65536) return;
    int g = t & 3, j = (t >> 2) & 255, k4 = t >> 10;   // k4: 0..63
    int row = g * 256 + j;
    float4 v = *(const float4*)(W + (size_t)row * 256 + k4 * 4);
    _Float16 h4[4] = {(_Float16)v.x, (_Float16)v.y, (_Float16)v.z, (_Float16)v.w};
    unsigned short* dst = (g < 2 ? Pif : Pgo) + ((size_t)(k4 * 256 + j) * 8 + (g & 1) * 4);
    *(unsigned long long*)dst = *(const unsigned long long*)h4;
}

// ---------------- f32 GEMM: C[M,N] = A[M,K] @ W[N,K]^T + bias (unchanged, passing) ----------------
template<int AMODE, int OUTT>
__global__ __launch_bounds__(256)
void gemm_kernel(const void* __restrict__ Aptr, const unsigned* __restrict__ words_u32,
                 const float* __restrict__ emb, const unsigned* __restrict__ dflags,
                 const float* __restrict__ Wlo, const float* __restrict__ Whi,
                 const float* __restrict__ blo, const float* __restrict__ bhi,
                 void* __restrict__ Cptr, int M, int N, int K)
{
    __shared__ float As[16][68];
    __shared__ float Ws[16][68];
    const int tx = threadIdx.x & 15, ty = threadIdx.x >> 4;
    const int m0 = blockIdx.y * 64, n0 = blockIdx.x * 64;
    const bool hi = ((m0 & 511) >= 256);
    const float* W = hi ? Whi : Wlo;
    const float* bias = hi ? bhi : blo;
    const int lr = threadIdx.x >> 2, lc = threadIdx.x & 3;
    bool w64 = false;
    if (AMODE == 2) w64 = (dflags[0] & 1u) != 0u;
    float acc[4][4] = {};
    for (int k0 = 0; k0 < K; k0 += 16) {
        float a4[4], w4[4];
        if (AMODE == 2) {
            int m = m0 + lr;
            int w = (int)(w64 ? words_u32[2 * m] : words_u32[m]);
            float4 v = *(const float4*)(emb + (size_t)w * Eq + k0 + lc * 4);
            a4[0] = v.x; a4[1] = v.y; a4[2] = v.z; a4[3] = v.w;
        } else if (AMODE == 0) {
            float4 v = *(const float4*)((const float*)Aptr + (size_t)(m0 + lr) * K + k0 + lc * 4);
            a4[0] = v.x; a4[1] = v.y; a4[2] = v.z; a4[3] = v.w;
        } else {
            const _Float16* Ab = (const _Float16*)Aptr + (size_t)(m0 + lr) * K + k0 + lc * 4;
            #pragma unroll
            for (int q = 0; q < 4; ++q) a4[q] = (float)Ab[q];
        }
        int nrow = n0 + lr;
        if (nrow < N) {
            float4 v = *(const float4*)(W + (size_t)nrow * K + k0 + lc * 4);
            w4[0] = v.x; w4[1] = v.y; w4[2] = v.z; w4[3] = v.w;
        } else { w4[0] = w4[1] = w4[2] = w4[3] = 0.f; }
        __syncthreads();
        #pragma unroll
        for (int q = 0; q < 4; ++q) {
            As[lc * 4 + q][lr] = a4[q];
            Ws[lc * 4 + q][lr] = w4[q];
        }
        __syncthreads();
        #pragma unroll
        for (int kk = 0; kk < 16; ++kk) {
            float4 a = *(const float4*)&As[kk][ty * 4];
            float4 w = *(const float4*)&Ws[kk][tx * 4];
            float av[4] = {a.x, a.y, a.z, a.w};
            float wv[4] = {w.x, w.y, w.z, w.w};
            #pragma unroll
            for (int i = 0; i < 4; ++i)
                #pragma unroll
                for (int j = 0; j < 4; ++j)
                    acc[i][j] += av[i] * wv[j];
        }
    }
    #pragma unroll
    for (int i = 0; i < 4; ++i) {
        int row = m0 + ty * 4 + i;
        #pragma unroll
        for (int j = 0; j < 4; ++j) {
            int col = n0 + tx * 4 + j;
            if (col < N) {
                float v = acc[i][j] + bias[col];
                if (OUTT == 1) ((_Float16*)Cptr)[(size_t)row * N + col] = (_Float16)v;
                else           ((float*)Cptr)[(size_t)row * N + col] = v;
            }
        }
    }
}

// ---------------- 4-batch zero-exchange LSTM, f16 W: regs(kq0-9) + LDS(kq10-11) + stream(kq12-15) ----------------
// 32 blocks x 1024 threads. thread = (q = tid>>8, j = tid&255).
// Same math/accumulation order (kq ascending) as rounds 13/14 -> bit-identical.
// VGPR: 80 W + ~32 working ~= 112 <= 128 (4 waves/SIMD preserved).
// OUTT: 0 = f32, 1 = f16
template<int OUTT>
__global__ __launch_bounds__(1024)
void lstm_f16w(const float* __restrict__ xg,      // [M][1024] phased
               const unsigned short* __restrict__ Pfif, const unsigned short* __restrict__ Pfgo,
               const unsigned short* __restrict__ Pbif, const unsigned short* __restrict__ Pbgo,
               const unsigned* __restrict__ len_u32,
               const unsigned* __restrict__ dflags,
               float* __restrict__ Hsav,          // [2][Bq][Hq]
               float* __restrict__ Csav,          // [2][Bq][Hq]
               void* __restrict__ out,            // [M][512]
               int t0, int t1)
{
    extern __shared__ char lds_raw[];
    float* scr = (float*)lds_raw;                                   // [4][4][4][256] 64KB
    unsigned short* wifl = (unsigned short*)(lds_raw + 65536);      // [4][2][256][8]  32KB
    unsigned short* wgol = (unsigned short*)(lds_raw + 65536 + 32768); // 32KB
    float* hsh = (float*)(lds_raw + 131072);                        // [4][256] 4KB
    unsigned short* hsh16 = (unsigned short*)(lds_raw + 135168);    // [4][256] 2KB

    const int tid = threadIdx.x;
    const int bid = blockIdx.x;
    const int dir = bid >> 4;
    const int b0  = (bid & 15) * 4;
    const int j   = tid & 255;
    const int q   = tid >> 8;            // k-quarter for matvec; batch index for update
    const unsigned short* __restrict__ Pif = dir ? Pbif : Pfif;
    const unsigned short* __restrict__ Pgo = dir ? Pbgo : Pfgo;
    const bool l64 = (dflags[0] & 2u) != 0u;

    const int bu = q;
    const int mylen = (int)(l64 ? len_u32[2 * (b0 + bu)] : len_u32[b0 + bu]);

    // stage kq 10..11 into LDS: idx = q*512 + kq2*256 + j  (2048 chunks x 16B per plane)
    for (int idx = tid; idx < 2048; idx += 1024) {
        int jj = idx & 255, kq2 = (idx >> 8) & 1, qq = idx >> 9;
        int gch = qq * 16 + 10 + kq2;
        *(uint4*)(wifl + (size_t)idx * 8) = *(const uint4*)(Pif + ((size_t)gch * 256 + jj) * 8);
        *(uint4*)(wgol + (size_t)idx * 8) = *(const uint4*)(Pgo + ((size_t)gch * 256 + jj) * 8);
    }
    // preload kq 0..9 into registers (live across all steps)
    uint4 wif_r[10], wgo_r[10];
    #pragma unroll
    for (int kq = 0; kq < 10; ++kq) {
        wif_r[kq] = *(const uint4*)(Pif + ((size_t)((q * 16 + kq) * 256 + j)) * 8);
        wgo_r[kq] = *(const uint4*)(Pgo + ((size_t)((q * 16 + kq) * 256 + j)) * 8);
    }

    float c = 0.f;
    {
        float h0;
        if (t0 == 0) {
            h0 = 0.f;
        } else {
            c  = Csav[((size_t)dir * Bq + b0 + bu) * Hq + j];
            h0 = Hsav[((size_t)dir * Bq + b0 + bu) * Hq + j];
        }
        hsh[bu * 256 + j] = h0;
        _Float16 hh = (_Float16)h0;
        hsh16[bu * 256 + j] = __builtin_bit_cast(unsigned short, hh);
    }
    __syncthreads();

    for (int t = t0; t < t1; ++t) {
        const int teff = dir ? (Tq - 1 - t) : t;
        const float* xr = xg + ((size_t)(b0 + bu) * Tq + teff) * 1024 + j;
        float xv0 = xr[0], xv1 = xr[256], xv2 = xr[512], xv3 = xr[768];

        float a[4][4] = {};   // [g][b]
        // kq 0..9 from registers
        #pragma unroll
        for (int kq = 0; kq < 10; ++kq) {
            uint4 wif = wif_r[kq], wgo = wgo_r[kq];
            #pragma unroll
            for (int b = 0; b < 4; ++b) {
                uint2 hv = *(const uint2*)(&hsh16[b * 256 + q * 64 + kq * 4]);
                a[0][b] = dot2_(wif.x, hv.x, a[0][b]);
                a[0][b] = dot2_(wif.y, hv.y, a[0][b]);
                a[1][b] = dot2_(wif.z, hv.x, a[1][b]);
                a[1][b] = dot2_(wif.w, hv.y, a[1][b]);
                a[2][b] = dot2_(wgo.x, hv.x, a[2][b]);
                a[2][b] = dot2_(wgo.y, hv.y, a[2][b]);
                a[3][b] = dot2_(wgo.z, hv.x, a[3][b]);
                a[3][b] = dot2_(wgo.w, hv.y, a[3][b]);
            }
        }
        // kq 10..11 from LDS
        #pragma unroll
        for (int kq2 = 0; kq2 < 2; ++kq2) {
            const int kq = 10 + kq2;
            uint4 wif = *(const uint4*)(wifl + ((size_t)((q * 2 + kq2) * 256 + j)) * 8);
            uint4 wgo = *(const uint4*)(wgol + ((size_t)((q * 2 + kq2) * 256 + j)) * 8);
            #pragma unroll
            for (int b = 0; b < 4; ++b) {
                uint2 hv = *(const uint2*)(&hsh16[b * 256 + q * 64 + kq * 4]);
                a[0][b] = dot2_(wif.x, hv.x, a[0][b]);
                a[0][b] = dot2_(wif.y, hv.y, a[0][b]);
                a[1][b] = dot2_(wif.z, hv.x, a[1][b]);
                a[1][b] = dot2_(wif.w, hv.y, a[1][b]);
                a[2][b] = dot2_(wgo.x, hv.x, a[2][b]);
                a[2][b] = dot2_(wgo.y, hv.y, a[2][b]);
                a[3][b] = dot2_(wgo.z, hv.x, a[3][b]);
                a[3][b] = dot2_(wgo.w, hv.y, a[3][b]);
            }
        }
        // kq 12..15 streamed from global (contiguous 1KB wave loads per plane)
        #pragma unroll 4
        for (int kq = 12; kq < 16; ++kq) {
            uint4 wif = *(const uint4*)(Pif + ((size_t)((q * 16 + kq) * 256 + j)) * 8);
            uint4 wgo = *(const uint4*)(Pgo + ((size_t)((q * 16 + kq) * 256 + j)) * 8);
            #pragma unroll
            for (int b = 0; b < 4; ++b) {
                uint2 hv = *(const uint2*)(&hsh16[b * 256 + q * 64 + kq * 4]);
                a[0][b] = dot2_(wif.x, hv.x, a[0][b]);
                a[0][b] = dot2_(wif.y, hv.y, a[0][b]);
                a[1][b] = dot2_(wif.z, hv.x, a[1][b]);
                a[1][b] = dot2_(wif.w, hv.y, a[1][b]);
                a[2][b] = dot2_(wgo.x, hv.x, a[2][b]);
                a[2][b] = dot2_(wgo.y, hv.y, a[2][b]);
                a[3][b] = dot2_(wgo.z, hv.x, a[3][b]);
                a[3][b] = dot2_(wgo.w, hv.y, a[3][b]);
            }
        }
        #pragma unroll
        for (int b = 0; b < 4; ++b)
            #pragma unroll
            for (int g = 0; g < 4; ++g)
                scr[((q * 4 + b) * 4 + g) * 256 + j] = a[g][b];
        __syncthreads();

        // update: thread (bu, j)
        {
            float g0 = xv0, g1 = xv1, g2 = xv2, g3 = xv3;
            #pragma unroll
            for (int qq = 0; qq < 4; ++qq) {
                g0 += scr[((qq * 4 + bu) * 4 + 0) * 256 + j];
                g1 += scr[((qq * 4 + bu) * 4 + 1) * 256 + j];
                g2 += scr[((qq * 4 + bu) * 4 + 2) * 256 + j];
                g3 += scr[((qq * 4 + bu) * 4 + 3) * 256 + j];
            }
            float ig = sigmoidf_(g0), fg = sigmoidf_(g1);
            float gg = tanhf_(g2), og = sigmoidf_(g3);
            float cn = fg * c + ig * gg;
            float hn = og * tanhf_(cn);
            bool m = (teff < mylen);
            float hold = hsh[bu * 256 + j];
            float hm = m ? hn : hold;
            c = m ? cn : c;
            hsh[bu * 256 + j] = hm;
            _Float16 hh = (_Float16)hm;
            hsh16[bu * 256 + j] = __builtin_bit_cast(unsigned short, hh);
            size_t orow = (size_t)(b0 + bu) * Tq + teff;
            if (OUTT == 1) ((_Float16*)out)[orow * 512 + dir * 256 + j] = (_Float16)hm;
            else           ((float*)out)[orow * 512 + dir * 256 + j] = hm;
        }
        __syncthreads();
    }
    Csav[((size_t)dir * Bq + b0 + bu) * Hq + j] = c;
    Hsav[((size_t)dir * Bq + b0 + bu) * Hq + j] = hsh[bu * 256 + j];
}

extern "C" void kernel_launch(void* const* d_in, const int* in_sizes, int n_in,
                              void* d_out, int out_size, void* d_ws, size_t ws_size,
                              hipStream_t stream)
{
    const unsigned* words  = (const unsigned*)d_in[0];
    const unsigned* lens   = (const unsigned*)d_in[1];
    const float* emb     = (const float*)d_in[2];
    const float* l1f_Wih = (const float*)d_in[3];
    const float* l1f_Whh = (const float*)d_in[4];
    const float* l1f_bih = (const float*)d_in[5];
    const float* l1f_bhh = (const float*)d_in[6];
    const float* l1b_Wih = (const float*)d_in[7];
    const float* l1b_Whh = (const float*)d_in[8];
    const float* l1b_bih = (const float*)d_in[9];
    const float* l1b_bhh = (const float*)d_in[10];
    const float* l2f_Wih = (const float*)d_in[11];
    const float* l2f_Whh = (const float*)d_in[12];
    const float* l2f_bih = (const float*)d_in[13];
    const float* l2f_bhh = (const float*)d_in[14];
    const float* l2b_Wih = (const float*)d_in[15];
    const float* l2b_Whh = (const float*)d_in[16];
    const float* l2b_bih = (const float*)d_in[17];
    const float* l2b_bhh = (const float*)d_in[18];
    const float* cls_W   = (const float*)d_in[19];
    const float* cls_b   = (const float*)d_in[20];
    (void)in_sizes; (void)n_in; (void)out_size; (void)ws_size;

    char* ws = (char*)d_ws;
    size_t off = 0;
    auto alloc = [&](size_t b) { void* p = ws + off; off += (b + 255) & ~(size_t)255; return p; };
    float*     xg = (float*)alloc((size_t)Mq * 1024 * 4);   // 128 MiB, reused 4x
    float*     o1 = (float*)alloc((size_t)Mq * 512 * 4);    // 64 MiB
    _Float16*  o2 = (_Float16*)alloc((size_t)Mq * 512 * 2); // 32 MiB
    unsigned short* Wpk = (unsigned short*)alloc((size_t)8 * 131072 * 2); // 2 MiB: 4 mats x 2 planes
    float*   Hsav = (float*)alloc((size_t)2 * Bq * Hq * 4);
    float*   Csav = (float*)alloc((size_t)2 * Bq * Hq * 4);
    float* biasbuf = (float*)alloc((size_t)4 * 1024 * 4);
    unsigned* dflags = (unsigned*)alloc(256);

    const float* b1f = biasbuf, *b1b = biasbuf + 1024, *b2f = biasbuf + 2048, *b2b = biasbuf + 3072;
    unsigned short* P1fif = Wpk;
    unsigned short* P1fgo = Wpk + 131072;
    unsigned short* P1bif = Wpk + 2 * 131072;
    unsigned short* P1bgo = Wpk + 3 * 131072;
    unsigned short* P2fif = Wpk + 4 * 131072;
    unsigned short* P2fgo = Wpk + 5 * 131072;
    unsigned short* P2bif = Wpk + 6 * 131072;
    unsigned short* P2bgo = Wpk + 7 * 131072;

    const size_t ldsBytes = 65536 + 32768 + 32768 + 4096 + 2048;   // 137216
    hipFuncSetAttribute((const void*)lstm_f16w<0>, hipFuncAttributeMaxDynamicSharedMemorySize, (int)ldsBytes);
    hipFuncSetAttribute((const void*)lstm_f16w<1>, hipFuncAttributeMaxDynamicSharedMemorySize, (int)ldsBytes);

    detect_int64<<<1, 256, 0, stream>>>(words, lens, dflags);
    bias_kernel<<<dim3(16), 256, 0, stream>>>(l1f_bih, l1f_bhh, l1b_bih, l1b_bhh,
                                              l2f_bih, l2f_bhh, l2b_bih, l2b_bhh, biasbuf);
    pack_whh16<<<dim3(256), 256, 0, stream>>>(l1f_Whh, P1fif, P1fgo);
    pack_whh16<<<dim3(256), 256, 0, stream>>>(l1b_Whh, P1bif, P1bgo);
    pack_whh16<<<dim3(256), 256, 0, stream>>>(l2f_Whh, P2fif, P2fgo);
    pack_whh16<<<dim3(256), 256, 0, stream>>>(l2b_Whh, P2bif, P2bgo);

    dim3 ggrid(1024 / 64, Mq / 64);
    // ---- layer 1 ----
    gemm_kernel<2, 0><<<ggrid, 256, 0, stream>>>(nullptr, words, emb, dflags,
        l1f_Wih, l1b_Wih, b1f, b1b, xg, Mq, 1024, Eq);
    lstm_f16w<0><<<32, 1024, ldsBytes, stream>>>(xg, P1fif, P1fgo, P1bif, P1bgo,
        lens, dflags, Hsav, Csav, o1, 0, 256);
    gemm_kernel<2, 0><<<ggrid, 256, 0, stream>>>(nullptr, words, emb, dflags,
        l1b_Wih, l1f_Wih, b1b, b1f, xg, Mq, 1024, Eq);
    lstm_f16w<0><<<32, 1024, ldsBytes, stream>>>(xg, P1fif, P1fgo, P1bif, P1bgo,
        lens, dflags, Hsav, Csav, o1, 256, 512);
    // ---- layer 2 ----
    gemm_kernel<0, 0><<<ggrid, 256, 0, stream>>>(o1, nullptr, nullptr, dflags,
        l2f_Wih, l2b_Wih, b2f, b2b, xg, Mq, 1024, 512);
    lstm_f16w<1><<<32, 1024, ldsBytes, stream>>>(xg, P2fif, P2fgo, P2bif, P2bgo,
        lens, dflags, Hsav, Csav, o2, 0, 256);
    gemm_kernel<0, 0><<<ggrid, 256, 0, stream>>>(o1, nullptr, nullptr, dflags,
        l2b_Wih, l2f_Wih, b2b, b2f, xg, Mq, 1024, 512);
    lstm_f16w<1><<<32, 1024, ldsBytes, stream>>>(xg, P2fif, P2fgo, P2bif, P2bgo,
        lens, dflags, Hsav, Csav, o2, 256, 512);
    // ---- classifier -> d_out (f32) ----
    gemm_kernel<3, 0><<<dim3(1, Mq / 64), 256, 0, stream>>>(o2, nullptr, nullptr, dflags,
        cls_W, cls_W, cls_b, cls_b, d_out, Mq, NTAGS, 512);
}

// Round 16
// 8087.970 us; speedup vs baseline: 1.2108x; 1.2108x over previous
//
#include <hip/hip_runtime.h>
#include <hip/hip_bf16.h>

#define Bq 64
#define Tq 512
#define Eq 128
#define Hq 256
#define NTAGS 50
#define Mq (Bq*Tq)   // 32768

typedef _Float16 half2_t __attribute__((ext_vector_type(2)));

__device__ __forceinline__ float sigmoidf_(float x) { return 1.f / (1.f + __expf(-x)); }
__device__ __forceinline__ float tanhf_(float x) {
    float e = __expf(2.f * x);
    return 1.f - 2.f / (e + 1.f);
}

#if __has_builtin(__builtin_amdgcn_fdot2)
__device__ __forceinline__ float dot2_(unsigned w, unsigned h, float acc) {
    return __builtin_amdgcn_fdot2(__builtin_bit_cast(half2_t, w),
                                  __builtin_bit_cast(half2_t, h), acc, false);
}
#else
__device__ __forceinline__ float dot2_(unsigned w, unsigned h, float acc) {
    half2_t wv = __builtin_bit_cast(half2_t, w);
    half2_t hv = __builtin_bit_cast(half2_t, h);
    return acc + (float)wv.x * (float)hv.x + (float)wv.y * (float)hv.y;
}
#endif

// ---------------- dtype detection: int32 vs int64 for words/lengths ----------------
__global__ void detect_int64(const unsigned* __restrict__ words,
                             const unsigned* __restrict__ lens,
                             unsigned* __restrict__ dflags) {
    __shared__ int wbad, lbad, wnz, lnz;
    if (threadIdx.x == 0) { wbad = 0; lbad = 0; wnz = 0; lnz = 0; }
    __syncthreads();
    for (int i = threadIdx.x; i < 16384; i += blockDim.x) {
        if (words[2 * i + 1] != 0u) wbad = 1;
        if (words[2 * i] != 0u) wnz = 1;
    }
    for (int i = threadIdx.x; i < 32; i += blockDim.x) {
        if (lens[2 * i + 1] != 0u) lbad = 1;
        if (lens[2 * i] != 0u) lnz = 1;
    }
    __syncthreads();
    if (threadIdx.x == 0) {
        unsigned f = 0;
        if (!wbad && wnz) f |= 1u;
        if (!lbad && lnz) f |= 2u;
        dflags[0] = f;
    }
}

// ---------------- bias: bias[l][d][n] = bih + bhh ----------------
__global__ void bias_kernel(const float* b1f_ih, const float* b1f_hh,
                            const float* b1b_ih, const float* b1b_hh,
                            const float* b2f_ih, const float* b2f_hh,
                            const float* b2b_ih, const float* b2b_hh,
                            float* bias) {   // [4][1024]: l1f,l1b,l2f,l2b
    int i = blockIdx.x * blockDim.x + threadIdx.x;
    if (i >= 4096) return;
    int l = i >> 11, d = (i >> 10) & 1, nn = i & 1023;
    float v;
    if (l == 0) v = d ? (b1b_ih[nn] + b1b_hh[nn]) : (b1f_ih[nn] + b1f_hh[nn]);
    else        v = d ? (b2b_ih[nn] + b2b_hh[nn]) : (b2f_ih[nn] + b2f_hh[nn]);
    bias[i] = v;
}

// ---------------- Whh f16 two-plane packing ----------------
// plane_if[(k4*256+j)*8 + g01*4 + kk] : gates 0,1 ; plane_go : gates 2,3.
__global__ void pack_whh16(const float* __restrict__ W,
                           unsigned short* __restrict__ Pif,
                           unsigned short* __restrict__ Pgo) {
    int t = blockIdx.x * 256 + threadIdx.x;   // 0..65535
    if (t >= 65536) return;
    int g = t & 3, j = (t >> 2) & 255, k4 = t >> 10;   // k4: 0..63
    int row = g * 256 + j;
    float4 v = *(const float4*)(W + (size_t)row * 256 + k4 * 4);
    _Float16 h4[4] = {(_Float16)v.x, (_Float16)v.y, (_Float16)v.z, (_Float16)v.w};
    unsigned short* dst = (g < 2 ? Pif : Pgo) + ((size_t)(k4 * 256 + j) * 8 + (g & 1) * 4);
    *(unsigned long long*)dst = *(const unsigned long long*)h4;
}

// ---------------- f32 GEMM: C[M,N] = A[M,K] @ W[N,K]^T + bias (unchanged, passing) ----------------
template<int AMODE, int OUTT>
__global__ __launch_bounds__(256)
void gemm_kernel(const void* __restrict__ Aptr, const unsigned* __restrict__ words_u32,
                 const float* __restrict__ emb, const unsigned* __restrict__ dflags,
                 const float* __restrict__ Wlo, const float* __restrict__ Whi,
                 const float* __restrict__ blo, const float* __restrict__ bhi,
                 void* __restrict__ Cptr, int M, int N, int K)
{
    __shared__ float As[16][68];
    __shared__ float Ws[16][68];
    const int tx = threadIdx.x & 15, ty = threadIdx.x >> 4;
    const int m0 = blockIdx.y * 64, n0 = blockIdx.x * 64;
    const bool hi = ((m0 & 511) >= 256);
    const float* W = hi ? Whi : Wlo;
    const float* bias = hi ? bhi : blo;
    const int lr = threadIdx.x >> 2, lc = threadIdx.x & 3;
    bool w64 = false;
    if (AMODE == 2) w64 = (dflags[0] & 1u) != 0u;
    float acc[4][4] = {};
    for (int k0 = 0; k0 < K; k0 += 16) {
        float a4[4], w4[4];
        if (AMODE == 2) {
            int m = m0 + lr;
            int w = (int)(w64 ? words_u32[2 * m] : words_u32[m]);
            float4 v = *(const float4*)(emb + (size_t)w * Eq + k0 + lc * 4);
            a4[0] = v.x; a4[1] = v.y; a4[2] = v.z; a4[3] = v.w;
        } else if (AMODE == 0) {
            float4 v = *(const float4*)((const float*)Aptr + (size_t)(m0 + lr) * K + k0 + lc * 4);
            a4[0] = v.x; a4[1] = v.y; a4[2] = v.z; a4[3] = v.w;
        } else {
            const _Float16* Ab = (const _Float16*)Aptr + (size_t)(m0 + lr) * K + k0 + lc * 4;
            #pragma unroll
            for (int q = 0; q < 4; ++q) a4[q] = (float)Ab[q];
        }
        int nrow = n0 + lr;
        if (nrow < N) {
            float4 v = *(const float4*)(W + (size_t)nrow * K + k0 + lc * 4);
            w4[0] = v.x; w4[1] = v.y; w4[2] = v.z; w4[3] = v.w;
        } else { w4[0] = w4[1] = w4[2] = w4[3] = 0.f; }
        __syncthreads();
        #pragma unroll
        for (int q = 0; q < 4; ++q) {
            As[lc * 4 + q][lr] = a4[q];
            Ws[lc * 4 + q][lr] = w4[q];
        }
        __syncthreads();
        #pragma unroll
        for (int kk = 0; kk < 16; ++kk) {
            float4 a = *(const float4*)&As[kk][ty * 4];
            float4 w = *(const float4*)&Ws[kk][tx * 4];
            float av[4] = {a.x, a.y, a.z, a.w};
            float wv[4] = {w.x, w.y, w.z, w.w};
            #pragma unroll
            for (int i = 0; i < 4; ++i)
                #pragma unroll
                for (int j = 0; j < 4; ++j)
                    acc[i][j] += av[i] * wv[j];
        }
    }
    #pragma unroll
    for (int i = 0; i < 4; ++i) {
        int row = m0 + ty * 4 + i;
        #pragma unroll
        for (int j = 0; j < 4; ++j) {
            int col = n0 + tx * 4 + j;
            if (col < N) {
                float v = acc[i][j] + bias[col];
                if (OUTT == 1) ((_Float16*)Cptr)[(size_t)row * N + col] = (_Float16)v;
                else           ((float*)Cptr)[(size_t)row * N + col] = v;
            }
        }
    }
}

// ---------------- 4-batch zero-exchange LSTM, f16 W: regs(kq0-7, asm-pinned) + LDS(kq8-9) + stream(kq10-15) ----------------
// 32 blocks x 1024 threads. thread = (q = tid>>8, j = tid&255).
// __launch_bounds__(1024, 4): 4 waves/EU min -> 1 block/CU -> VGPR cap 128
// (LDS 137KB forces 1 block/CU anyway; this just unlocks the register file).
// asm keep-alive pins the W preload against rematerialization (round-15 failure).
// Accumulation kq-ascending, identical op order -> bit-identical to rounds 13-15.
// OUTT: 0 = f32, 1 = f16
template<int OUTT>
__global__ __launch_bounds__(1024, 4)
void lstm_f16w(const float* __restrict__ xg,      // [M][1024] phased
               const unsigned short* __restrict__ Pfif, const unsigned short* __restrict__ Pfgo,
               const unsigned short* __restrict__ Pbif, const unsigned short* __restrict__ Pbgo,
               const unsigned* __restrict__ len_u32,
               const unsigned* __restrict__ dflags,
               float* __restrict__ Hsav,          // [2][Bq][Hq]
               float* __restrict__ Csav,          // [2][Bq][Hq]
               void* __restrict__ out,            // [M][512]
               int t0, int t1)
{
    extern __shared__ char lds_raw[];
    float* scr = (float*)lds_raw;                                   // [4][4][4][256] 64KB
    unsigned short* wifl = (unsigned short*)(lds_raw + 65536);      // [4][2][256][8]  32KB
    unsigned short* wgol = (unsigned short*)(lds_raw + 65536 + 32768); // 32KB
    float* hsh = (float*)(lds_raw + 131072);                        // [4][256] 4KB
    unsigned short* hsh16 = (unsigned short*)(lds_raw + 135168);    // [4][256] 2KB

    const int tid = threadIdx.x;
    const int bid = blockIdx.x;
    const int dir = bid >> 4;
    const int b0  = (bid & 15) * 4;
    const int j   = tid & 255;
    const int q   = tid >> 8;            // k-quarter for matvec; batch index for update
    const unsigned short* __restrict__ Pif = dir ? Pbif : Pfif;
    const unsigned short* __restrict__ Pgo = dir ? Pbgo : Pfgo;
    const bool l64 = (dflags[0] & 2u) != 0u;

    const int bu = q;
    const int mylen = (int)(l64 ? len_u32[2 * (b0 + bu)] : len_u32[b0 + bu]);

    // stage kq 8..9 into LDS: idx = q*512 + kq2*256 + j  (2048 chunks x 16B per plane)
    for (int idx = tid; idx < 2048; idx += 1024) {
        int jj = idx & 255, kq2 = (idx >> 8) & 1, qq = idx >> 9;
        int gch = qq * 16 + 8 + kq2;
        *(uint4*)(wifl + (size_t)idx * 8) = *(const uint4*)(Pif + ((size_t)gch * 256 + jj) * 8);
        *(uint4*)(wgol + (size_t)idx * 8) = *(const uint4*)(Pgo + ((size_t)gch * 256 + jj) * 8);
    }
    // preload kq 0..7 into registers, pinned with asm keep-alive so the
    // compiler cannot rematerialize the loads inside the t-loop (round-15 bug).
    uint4 wif_r[8], wgo_r[8];
    #pragma unroll
    for (int kq = 0; kq < 8; ++kq) {
        wif_r[kq] = *(const uint4*)(Pif + ((size_t)((q * 16 + kq) * 256 + j)) * 8);
        wgo_r[kq] = *(const uint4*)(Pgo + ((size_t)((q * 16 + kq) * 256 + j)) * 8);
    }
    #pragma unroll
    for (int kq = 0; kq < 8; ++kq) {
        asm volatile("" : "+v"(wif_r[kq].x), "+v"(wif_r[kq].y),
                          "+v"(wif_r[kq].z), "+v"(wif_r[kq].w));
        asm volatile("" : "+v"(wgo_r[kq].x), "+v"(wgo_r[kq].y),
                          "+v"(wgo_r[kq].z), "+v"(wgo_r[kq].w));
    }

    float c = 0.f;
    {
        float h0;
        if (t0 == 0) {
            h0 = 0.f;
        } else {
            c  = Csav[((size_t)dir * Bq + b0 + bu) * Hq + j];
            h0 = Hsav[((size_t)dir * Bq + b0 + bu) * Hq + j];
        }
        hsh[bu * 256 + j] = h0;
        _Float16 hh = (_Float16)h0;
        hsh16[bu * 256 + j] = __builtin_bit_cast(unsigned short, hh);
    }
    __syncthreads();

    for (int t = t0; t < t1; ++t) {
        const int teff = dir ? (Tq - 1 - t) : t;
        const float* xr = xg + ((size_t)(b0 + bu) * Tq + teff) * 1024 + j;
        float xv0 = xr[0], xv1 = xr[256], xv2 = xr[512], xv3 = xr[768];

        float a[4][4] = {};   // [g][b]
        // kq 0..7 from registers
        #pragma unroll
        for (int kq = 0; kq < 8; ++kq) {
            uint4 wif = wif_r[kq], wgo = wgo_r[kq];
            #pragma unroll
            for (int b = 0; b < 4; ++b) {
                uint2 hv = *(const uint2*)(&hsh16[b * 256 + q * 64 + kq * 4]);
                a[0][b] = dot2_(wif.x, hv.x, a[0][b]);
                a[0][b] = dot2_(wif.y, hv.y, a[0][b]);
                a[1][b] = dot2_(wif.z, hv.x, a[1][b]);
                a[1][b] = dot2_(wif.w, hv.y, a[1][b]);
                a[2][b] = dot2_(wgo.x, hv.x, a[2][b]);
                a[2][b] = dot2_(wgo.y, hv.y, a[2][b]);
                a[3][b] = dot2_(wgo.z, hv.x, a[3][b]);
                a[3][b] = dot2_(wgo.w, hv.y, a[3][b]);
            }
        }
        // kq 8..9 from LDS
        #pragma unroll
        for (int kq2 = 0; kq2 < 2; ++kq2) {
            const int kq = 8 + kq2;
            uint4 wif = *(const uint4*)(wifl + ((size_t)((q * 2 + kq2) * 256 + j)) * 8);
            uint4 wgo = *(const uint4*)(wgol + ((size_t)((q * 2 + kq2) * 256 + j)) * 8);
            #pragma unroll
            for (int b = 0; b < 4; ++b) {
                uint2 hv = *(const uint2*)(&hsh16[b * 256 + q * 64 + kq * 4]);
                a[0][b] = dot2_(wif.x, hv.x, a[0][b]);
                a[0][b] = dot2_(wif.y, hv.y, a[0][b]);
                a[1][b] = dot2_(wif.z, hv.x, a[1][b]);
                a[1][b] = dot2_(wif.w, hv.y, a[1][b]);
                a[2][b] = dot2_(wgo.x, hv.x, a[2][b]);
                a[2][b] = dot2_(wgo.y, hv.y, a[2][b]);
                a[3][b] = dot2_(wgo.z, hv.x, a[3][b]);
                a[3][b] = dot2_(wgo.w, hv.y, a[3][b]);
            }
        }
        // kq 10..15 streamed from global (contiguous 1KB wave loads per plane)
        #pragma unroll 3
        for (int kq = 10; kq < 16; ++kq) {
            uint4 wif = *(const uint4*)(Pif + ((size_t)((q * 16 + kq) * 256 + j)) * 8);
            uint4 wgo = *(const uint4*)(Pgo + ((size_t)((q * 16 + kq) * 256 + j)) * 8);
            #pragma unroll
            for (int b = 0; b < 4; ++b) {
                uint2 hv = *(const uint2*)(&hsh16[b * 256 + q * 64 + kq * 4]);
                a[0][b] = dot2_(wif.x, hv.x, a[0][b]);
                a[0][b] = dot2_(wif.y, hv.y, a[0][b]);
                a[1][b] = dot2_(wif.z, hv.x, a[1][b]);
                a[1][b] = dot2_(wif.w, hv.y, a[1][b]);
                a[2][b] = dot2_(wgo.x, hv.x, a[2][b]);
                a[2][b] = dot2_(wgo.y, hv.y, a[2][b]);
                a[3][b] = dot2_(wgo.z, hv.x, a[3][b]);
                a[3][b] = dot2_(wgo.w, hv.y, a[3][b]);
            }
        }
        #pragma unroll
        for (int b = 0; b < 4; ++b)
            #pragma unroll
            for (int g = 0; g < 4; ++g)
                scr[((q * 4 + b) * 4 + g) * 256 + j] = a[g][b];
        __syncthreads();

        // update: thread (bu, j)
        {
            float g0 = xv0, g1 = xv1, g2 = xv2, g3 = xv3;
            #pragma unroll
            for (int qq = 0; qq < 4; ++qq) {
                g0 += scr[((qq * 4 + bu) * 4 + 0) * 256 + j];
                g1 += scr[((qq * 4 + bu) * 4 + 1) * 256 + j];
                g2 += scr[((qq * 4 + bu) * 4 + 2) * 256 + j];
                g3 += scr[((qq * 4 + bu) * 4 + 3) * 256 + j];
            }
            float ig = sigmoidf_(g0), fg = sigmoidf_(g1);
            float gg = tanhf_(g2), og = sigmoidf_(g3);
            float cn = fg * c + ig * gg;
            float hn = og * tanhf_(cn);
            bool m = (teff < mylen);
            float hold = hsh[bu * 256 + j];
            float hm = m ? hn : hold;
            c = m ? cn : c;
            hsh[bu * 256 + j] = hm;
            _Float16 hh = (_Float16)hm;
            hsh16[bu * 256 + j] = __builtin_bit_cast(unsigned short, hh);
            size_t orow = (size_t)(b0 + bu) * Tq + teff;
            if (OUTT == 1) ((_Float16*)out)[orow * 512 + dir * 256 + j] = (_Float16)hm;
            else           ((float*)out)[orow * 512 + dir * 256 + j] = hm;
        }
        __syncthreads();
    }
    Csav[((size_t)dir * Bq + b0 + bu) * Hq + j] = c;
    Hsav[((size_t)dir * Bq + b0 + bu) * Hq + j] = hsh[bu * 256 + j];
}

extern "C" void kernel_launch(void* const* d_in, const int* in_sizes, int n_in,
                              void* d_out, int out_size, void* d_ws, size_t ws_size,
                              hipStream_t stream)
{
    const unsigned* words  = (const unsigned*)d_in[0];
    const unsigned* lens   = (const unsigned*)d_in[1];
    const float* emb     = (const float*)d_in[2];
    const float* l1f_Wih = (const float*)d_in[3];
    const float* l1f_Whh = (const float*)d_in[4];
    const float* l1f_bih = (const float*)d_in[5];
    const float* l1f_bhh = (const float*)d_in[6];
    const float* l1b_Wih = (const float*)d_in[7];
    const float* l1b_Whh = (const float*)d_in[8];
    const float* l1b_bih = (const float*)d_in[9];
    const float* l1b_bhh = (const float*)d_in[10];
    const float* l2f_Wih = (const float*)d_in[11];
    const float* l2f_Whh = (const float*)d_in[12];
    const float* l2f_bih = (const float*)d_in[13];
    const float* l2f_bhh = (const float*)d_in[14];
    const float* l2b_Wih = (const float*)d_in[15];
    const float* l2b_Whh = (const float*)d_in[16];
    const float* l2b_bih = (const float*)d_in[17];
    const float* l2b_bhh = (const float*)d_in[18];
    const float* cls_W   = (const float*)d_in[19];
    const float* cls_b   = (const float*)d_in[20];
    (void)in_sizes; (void)n_in; (void)out_size; (void)ws_size;

    char* ws = (char*)d_ws;
    size_t off = 0;
    auto alloc = [&](size_t b) { void* p = ws + off; off += (b + 255) & ~(size_t)255; return p; };
    float*     xg = (float*)alloc((size_t)Mq * 1024 * 4);   // 128 MiB, reused 4x
    float*     o1 = (float*)alloc((size_t)Mq * 512 * 4);    // 64 MiB
    _Float16*  o2 = (_Float16*)alloc((size_t)Mq * 512 * 2); // 32 MiB
    unsigned short* Wpk = (unsigned short*)alloc((size_t)8 * 131072 * 2); // 2 MiB: 4 mats x 2 planes
    float*   Hsav = (float*)alloc((size_t)2 * Bq * Hq * 4);
    float*   Csav = (float*)alloc((size_t)2 * Bq * Hq * 4);
    float* biasbuf = (float*)alloc((size_t)4 * 1024 * 4);
    unsigned* dflags = (unsigned*)alloc(256);

    const float* b1f = biasbuf, *b1b = biasbuf + 1024, *b2f = biasbuf + 2048, *b2b = biasbuf + 3072;
    unsigned short* P1fif = Wpk;
    unsigned short* P1fgo = Wpk + 131072;
    unsigned short* P1bif = Wpk + 2 * 131072;
    unsigned short* P1bgo = Wpk + 3 * 131072;
    unsigned short* P2fif = Wpk + 4 * 131072;
    unsigned short* P2fgo = Wpk + 5 * 131072;
    unsigned short* P2bif = Wpk + 6 * 131072;
    unsigned short* P2bgo = Wpk + 7 * 131072;

    const size_t ldsBytes = 65536 + 32768 + 32768 + 4096 + 2048;   // 137216
    hipFuncSetAttribute((const void*)lstm_f16w<0>, hipFuncAttributeMaxDynamicSharedMemorySize, (int)ldsBytes);
    hipFuncSetAttribute((const void*)lstm_f16w<1>, hipFuncAttributeMaxDynamicSharedMemorySize, (int)ldsBytes);

    detect_int64<<<1, 256, 0, stream>>>(words, lens, dflags);
    bias_kernel<<<dim3(16), 256, 0, stream>>>(l1f_bih, l1f_bhh, l1b_bih, l1b_bhh,
                                              l2f_bih, l2f_bhh, l2b_bih, l2b_bhh, biasbuf);
    pack_whh16<<<dim3(256), 256, 0, stream>>>(l1f_Whh, P1fif, P1fgo);
    pack_whh16<<<dim3(256), 256, 0, stream>>>(l1b_Whh, P1bif, P1bgo);
    pack_whh16<<<dim3(256), 256, 0, stream>>>(l2f_Whh, P2fif, P2fgo);
    pack_whh16<<<dim3(256), 256, 0, stream>>>(l2b_Whh, P2bif, P2bgo);

    dim3 ggrid(1024 / 64, Mq / 64);
    // ---- layer 1 ----
    gemm_kernel<2, 0><<<ggrid, 256, 0, stream>>>(nullptr, words, emb, dflags,
        l1f_Wih, l1b_Wih, b1f, b1b, xg, Mq, 1024, Eq);
    lstm_f16w<0><<<32, 1024, ldsBytes, stream>>>(xg, P1fif, P1fgo, P1bif, P1bgo,
        lens, dflags, Hsav, Csav, o1, 0, 256);
    gemm_kernel<2, 0><<<ggrid, 256, 0, stream>>>(nullptr, words, emb, dflags,
        l1b_Wih, l1f_Wih, b1b, b1f, xg, Mq, 1024, Eq);
    lstm_f16w<0><<<32, 1024, ldsBytes, stream>>>(xg, P1fif, P1fgo, P1bif, P1bgo,
        lens, dflags, Hsav, Csav, o1, 256, 512);
    // ---- layer 2 ----
    gemm_kernel<0, 0><<<ggrid, 256, 0, stream>>>(o1, nullptr, nullptr, dflags,
        l2f_Wih, l2b_Wih, b2f, b2b, xg, Mq, 1024, 512);
    lstm_f16w<1><<<32, 1024, ldsBytes, stream>>>(xg, P2fif, P2fgo, P2bif, P2bgo,
        lens, dflags, Hsav, Csav, o2, 0, 256);
    gemm_kernel<0, 0><<<ggrid, 256, 0, stream>>>(o1, nullptr, nullptr, dflags,
        l2b_Wih, l2f_Wih, b2b, b2f, xg, Mq, 1024, 512);
    lstm_f16w<1><<<32, 1024, ldsBytes, stream>>>(xg, P2fif, P2fgo, P2bif, P2bgo,
        lens, dflags, Hsav, Csav, o2, 256, 512);
    // ---- classifier -> d_out (f32) ----
    gemm_kernel<3, 0><<<dim3(1, Mq / 64), 256, 0, stream>>>(o2, nullptr, nullptr, dflags,
        cls_W, cls_W, cls_b, cls_b, d_out, Mq, NTAGS, 512);
}

// Round 17
// 7463.420 us; speedup vs baseline: 1.3121x; 1.0837x over previous
//
#include <hip/hip_runtime.h>
#include <hip/hip_bf16.h>

#define Bq 64
#define Tq 512
#define Eq 128
#define Hq 256
#define NTAGS 50
#define Mq (Bq*Tq)   // 32768

typedef _Float16 half2_t __attribute__((ext_vector_type(2)));

__device__ __forceinline__ float sigmoidf_(float x) { return 1.f / (1.f + __expf(-x)); }
__device__ __forceinline__ float tanhf_(float x) {
    float e = __expf(2.f * x);
    return 1.f - 2.f / (e + 1.f);
}

#if __has_builtin(__builtin_amdgcn_fdot2)
__device__ __forceinline__ float dot2_(unsigned w, unsigned h, float acc) {
    return __builtin_amdgcn_fdot2(__builtin_bit_cast(half2_t, w),
                                  __builtin_bit_cast(half2_t, h), acc, false);
}
#else
__device__ __forceinline__ float dot2_(unsigned w, unsigned h, float acc) {
    half2_t wv = __builtin_bit_cast(half2_t, w);
    half2_t hv = __builtin_bit_cast(half2_t, h);
    return acc + (float)wv.x * (float)hv.x + (float)wv.y * (float)hv.y;
}
#endif

// ---------------- dtype detection: int32 vs int64 for words/lengths ----------------
__global__ void detect_int64(const unsigned* __restrict__ words,
                             const unsigned* __restrict__ lens,
                             unsigned* __restrict__ dflags) {
    __shared__ int wbad, lbad, wnz, lnz;
    if (threadIdx.x == 0) { wbad = 0; lbad = 0; wnz = 0; lnz = 0; }
    __syncthreads();
    for (int i = threadIdx.x; i < 16384; i += blockDim.x) {
        if (words[2 * i + 1] != 0u) wbad = 1;
        if (words[2 * i] != 0u) wnz = 1;
    }
    for (int i = threadIdx.x; i < 32; i += blockDim.x) {
        if (lens[2 * i + 1] != 0u) lbad = 1;
        if (lens[2 * i] != 0u) lnz = 1;
    }
    __syncthreads();
    if (threadIdx.x == 0) {
        unsigned f = 0;
        if (!wbad && wnz) f |= 1u;
        if (!lbad && lnz) f |= 2u;
        dflags[0] = f;
    }
}

// ---------------- bias: bias[l][d][n] = bih + bhh ----------------
__global__ void bias_kernel(const float* b1f_ih, const float* b1f_hh,
                            const float* b1b_ih, const float* b1b_hh,
                            const float* b2f_ih, const float* b2f_hh,
                            const float* b2b_ih, const float* b2b_hh,
                            float* bias) {   // [4][1024]: l1f,l1b,l2f,l2b
    int i = blockIdx.x * blockDim.x + threadIdx.x;
    if (i >= 4096) return;
    int l = i >> 11, d = (i >> 10) & 1, nn = i & 1023;
    float v;
    if (l == 0) v = d ? (b1b_ih[nn] + b1b_hh[nn]) : (b1f_ih[nn] + b1f_hh[nn]);
    else        v = d ? (b2b_ih[nn] + b2b_hh[nn]) : (b2f_ih[nn] + b2f_hh[nn]);
    bias[i] = v;
}

// ---------------- Whh f16 two-plane packing ----------------
// plane_if[(k4*256+j)*8 + g01*4 + kk] : gates 0,1 ; plane_go : gates 2,3.
__global__ void pack_whh16(const float* __restrict__ W,
                           unsigned short* __restrict__ Pif,
                           unsigned short* __restrict__ Pgo) {
    int t = blockIdx.x * 256 + threadIdx.x;   // 0..65535
    if (t >= 65536) return;
    int g = t & 3, j = (t >> 2) & 255, k4 = t >> 10;   // k4: 0..63
    int row = g * 256 + j;
    float4 v = *(const float4*)(W + (size_t)row * 256 + k4 * 4);
    _Float16 h4[4] = {(_Float16)v.x, (_Float16)v.y, (_Float16)v.z, (_Float16)v.w};
    unsigned short* dst = (g < 2 ? Pif : Pgo) + ((size_t)(k4 * 256 + j) * 8 + (g & 1) * 4);
    *(unsigned long long*)dst = *(const unsigned long long*)h4;
}

// ---------------- f32 GEMM: C[M,N] = A[M,K] @ W[N,K]^T + bias (unchanged, passing) ----------------
template<int AMODE, int OUTT>
__global__ __launch_bounds__(256)
void gemm_kernel(const void* __restrict__ Aptr, const unsigned* __restrict__ words_u32,
                 const float* __restrict__ emb, const unsigned* __restrict__ dflags,
                 const float* __restrict__ Wlo, const float* __restrict__ Whi,
                 const float* __restrict__ blo, const float* __restrict__ bhi,
                 void* __restrict__ Cptr, int M, int N, int K)
{
    __shared__ float As[16][68];
    __shared__ float Ws[16][68];
    const int tx = threadIdx.x & 15, ty = threadIdx.x >> 4;
    const int m0 = blockIdx.y * 64, n0 = blockIdx.x * 64;
    const bool hi = ((m0 & 511) >= 256);
    const float* W = hi ? Whi : Wlo;
    const float* bias = hi ? bhi : blo;
    const int lr = threadIdx.x >> 2, lc = threadIdx.x & 3;
    bool w64 = false;
    if (AMODE == 2) w64 = (dflags[0] & 1u) != 0u;
    float acc[4][4] = {};
    for (int k0 = 0; k0 < K; k0 += 16) {
        float a4[4], w4[4];
        if (AMODE == 2) {
            int m = m0 + lr;
            int w = (int)(w64 ? words_u32[2 * m] : words_u32[m]);
            float4 v = *(const float4*)(emb + (size_t)w * Eq + k0 + lc * 4);
            a4[0] = v.x; a4[1] = v.y; a4[2] = v.z; a4[3] = v.w;
        } else if (AMODE == 0) {
            float4 v = *(const float4*)((const float*)Aptr + (size_t)(m0 + lr) * K + k0 + lc * 4);
            a4[0] = v.x; a4[1] = v.y; a4[2] = v.z; a4[3] = v.w;
        } else {
            const _Float16* Ab = (const _Float16*)Aptr + (size_t)(m0 + lr) * K + k0 + lc * 4;
            #pragma unroll
            for (int q = 0; q < 4; ++q) a4[q] = (float)Ab[q];
        }
        int nrow = n0 + lr;
        if (nrow < N) {
            float4 v = *(const float4*)(W + (size_t)nrow * K + k0 + lc * 4);
            w4[0] = v.x; w4[1] = v.y; w4[2] = v.z; w4[3] = v.w;
        } else { w4[0] = w4[1] = w4[2] = w4[3] = 0.f; }
        __syncthreads();
        #pragma unroll
        for (int q = 0; q < 4; ++q) {
            As[lc * 4 + q][lr] = a4[q];
            Ws[lc * 4 + q][lr] = w4[q];
        }
        __syncthreads();
        #pragma unroll
        for (int kk = 0; kk < 16; ++kk) {
            float4 a = *(const float4*)&As[kk][ty * 4];
            float4 w = *(const float4*)&Ws[kk][tx * 4];
            float av[4] = {a.x, a.y, a.z, a.w};
            float wv[4] = {w.x, w.y, w.z, w.w};
            #pragma unroll
            for (int i = 0; i < 4; ++i)
                #pragma unroll
                for (int j = 0; j < 4; ++j)
                    acc[i][j] += av[i] * wv[j];
        }
    }
    #pragma unroll
    for (int i = 0; i < 4; ++i) {
        int row = m0 + ty * 4 + i;
        #pragma unroll
        for (int j = 0; j < 4; ++j) {
            int col = n0 + tx * 4 + j;
            if (col < N) {
                float v = acc[i][j] + bias[col];
                if (OUTT == 1) ((_Float16*)Cptr)[(size_t)row * N + col] = (_Float16)v;
                else           ((float*)Cptr)[(size_t)row * N + col] = v;
            }
        }
    }
}

// ---------------- 4-batch zero-exchange LSTM, shuffle-reduce, parity-h ----------------
// 32 blocks x 1024 threads. lane = q*16 + jlo (q in lane bits 4-5), j = jhi*16+jlo.
// Matvec: thread (q,j) computes partials of gate rows {g*256+j} over k in
// [q*64, q*64+64) for all 4 batches. q-reduction via 2x __shfl_xor (in-wave,
// no LDS scr, no mid-step barrier). W residency: regs kq0-3 (round-14-proven),
// LDS kq4-7 (128KB, freed by scr removal), stream kq8-15 (256KB/step).
// h: own value in register; cross-thread h as f16 in parity double buffer ->
// single __syncthreads per step (write buffer != read buffer).
// OUTT: 0 = f32, 1 = f16
template<int OUTT>
__global__ __launch_bounds__(1024)
void lstm_shfl(const float* __restrict__ xg,      // [M][1024] phased
               const unsigned short* __restrict__ Pfif, const unsigned short* __restrict__ Pfgo,
               const unsigned short* __restrict__ Pbif, const unsigned short* __restrict__ Pbgo,
               const unsigned* __restrict__ len_u32,
               const unsigned* __restrict__ dflags,
               float* __restrict__ Hsav,          // [2][Bq][Hq]
               float* __restrict__ Csav,          // [2][Bq][Hq]
               void* __restrict__ out,            // [M][512]
               int t0, int t1)
{
    extern __shared__ char lds_raw[];
    unsigned short* wifl  = (unsigned short*)lds_raw;              // [4kq][4q][256][8] 64KB
    unsigned short* wgol  = (unsigned short*)(lds_raw + 65536);    // 64KB
    unsigned short* hsh16 = (unsigned short*)(lds_raw + 131072);   // [2][4][256] 4KB

    const int tid = threadIdx.x;
    const int bid = blockIdx.x;
    const int dir = bid >> 4;
    const int b0  = (bid & 15) * 4;
    const int jlo = tid & 15;
    const int q   = (tid >> 4) & 3;     // k-quarter AND update-batch index
    const int jhi = tid >> 6;
    const int j   = jhi * 16 + jlo;
    const int bu  = q;
    const unsigned short* __restrict__ Pif = dir ? Pbif : Pfif;
    const unsigned short* __restrict__ Pgo = dir ? Pbgo : Pfgo;
    const bool l64 = (dflags[0] & 2u) != 0u;
    const int mylen = (int)(l64 ? len_u32[2 * (b0 + bu)] : len_u32[b0 + bu]);

    // stage kq 4..7 into LDS: dst idx = (kql*4 + qq)*256 + jj
    for (int idx = tid; idx < 4096; idx += 1024) {
        int jj = idx & 255, qq = (idx >> 8) & 3, kql = idx >> 10;
        int k4 = qq * 16 + 4 + kql;
        *(uint4*)(wifl + (size_t)idx * 8) = *(const uint4*)(Pif + ((size_t)k4 * 256 + jj) * 8);
        *(uint4*)(wgol + (size_t)idx * 8) = *(const uint4*)(Pgo + ((size_t)k4 * 256 + jj) * 8);
    }
    // preload kq 0..3 into registers (round-14-proven pattern, no pins)
    uint4 wif_r[4], wgo_r[4];
    #pragma unroll
    for (int kq = 0; kq < 4; ++kq) {
        wif_r[kq] = *(const uint4*)(Pif + ((size_t)((q * 16 + kq) * 256 + j)) * 8);
        wgo_r[kq] = *(const uint4*)(Pgo + ((size_t)((q * 16 + kq) * 256 + j)) * 8);
    }

    float c = 0.f, hreg;
    {
        if (t0 == 0) {
            hreg = 0.f;
        } else {
            c    = Csav[((size_t)dir * Bq + b0 + bu) * Hq + j];
            hreg = Hsav[((size_t)dir * Bq + b0 + bu) * Hq + j];
        }
        _Float16 hh = (_Float16)hreg;
        hsh16[(t0 & 1) * 1024 + bu * 256 + j] = __builtin_bit_cast(unsigned short, hh);
    }
    __syncthreads();

    for (int t = t0; t < t1; ++t) {
        const int teff = dir ? (Tq - 1 - t) : t;
        const int par = t & 1;
        const unsigned short* hrd = hsh16 + par * 1024;
        unsigned short* hwr = hsh16 + (par ^ 1) * 1024;

        const float* xr = xg + ((size_t)(b0 + bu) * Tq + teff) * 1024 + j;
        float xv0 = xr[0], xv1 = xr[256], xv2 = xr[512], xv3 = xr[768];

        float a[4][4] = {};   // [g][b]
        // kq 0..3 from registers
        #pragma unroll
        for (int kq = 0; kq < 4; ++kq) {
            uint4 wif = wif_r[kq], wgo = wgo_r[kq];
            #pragma unroll
            for (int b = 0; b < 4; ++b) {
                uint2 hv = *(const uint2*)(hrd + b * 256 + q * 64 + kq * 4);
                a[0][b] = dot2_(wif.x, hv.x, a[0][b]);
                a[0][b] = dot2_(wif.y, hv.y, a[0][b]);
                a[1][b] = dot2_(wif.z, hv.x, a[1][b]);
                a[1][b] = dot2_(wif.w, hv.y, a[1][b]);
                a[2][b] = dot2_(wgo.x, hv.x, a[2][b]);
                a[2][b] = dot2_(wgo.y, hv.y, a[2][b]);
                a[3][b] = dot2_(wgo.z, hv.x, a[3][b]);
                a[3][b] = dot2_(wgo.w, hv.y, a[3][b]);
            }
        }
        // kq 4..7 from LDS
        #pragma unroll
        for (int kql = 0; kql < 4; ++kql) {
            const int kq = 4 + kql;
            uint4 wif = *(const uint4*)(wifl + ((size_t)((kql * 4 + q) * 256 + j)) * 8);
            uint4 wgo = *(const uint4*)(wgol + ((size_t)((kql * 4 + q) * 256 + j)) * 8);
            #pragma unroll
            for (int b = 0; b < 4; ++b) {
                uint2 hv = *(const uint2*)(hrd + b * 256 + q * 64 + kq * 4);
                a[0][b] = dot2_(wif.x, hv.x, a[0][b]);
                a[0][b] = dot2_(wif.y, hv.y, a[0][b]);
                a[1][b] = dot2_(wif.z, hv.x, a[1][b]);
                a[1][b] = dot2_(wif.w, hv.y, a[1][b]);
                a[2][b] = dot2_(wgo.x, hv.x, a[2][b]);
                a[2][b] = dot2_(wgo.y, hv.y, a[2][b]);
                a[3][b] = dot2_(wgo.z, hv.x, a[3][b]);
                a[3][b] = dot2_(wgo.w, hv.y, a[3][b]);
            }
        }
        // kq 8..15 streamed from global
        #pragma unroll 4
        for (int kq = 8; kq < 16; ++kq) {
            uint4 wif = *(const uint4*)(Pif + ((size_t)((q * 16 + kq) * 256 + j)) * 8);
            uint4 wgo = *(const uint4*)(Pgo + ((size_t)((q * 16 + kq) * 256 + j)) * 8);
            #pragma unroll
            for (int b = 0; b < 4; ++b) {
                uint2 hv = *(const uint2*)(hrd + b * 256 + q * 64 + kq * 4);
                a[0][b] = dot2_(wif.x, hv.x, a[0][b]);
                a[0][b] = dot2_(wif.y, hv.y, a[0][b]);
                a[1][b] = dot2_(wif.z, hv.x, a[1][b]);
                a[1][b] = dot2_(wif.w, hv.y, a[1][b]);
                a[2][b] = dot2_(wgo.x, hv.x, a[2][b]);
                a[2][b] = dot2_(wgo.y, hv.y, a[2][b]);
                a[3][b] = dot2_(wgo.z, hv.x, a[3][b]);
                a[3][b] = dot2_(wgo.w, hv.y, a[3][b]);
            }
        }
        // in-wave q-reduction (lanes differ in bits 4,5) + select own batch
        float gv0, gv1, gv2, gv3;
        {
            float r0, r1, r2, r3;
            #define REDUCE_G(gi, dst)                                        \
                r0 = a[gi][0]; r1 = a[gi][1]; r2 = a[gi][2]; r3 = a[gi][3];  \
                r0 += __shfl_xor(r0, 16); r0 += __shfl_xor(r0, 32);          \
                r1 += __shfl_xor(r1, 16); r1 += __shfl_xor(r1, 32);          \
                r2 += __shfl_xor(r2, 16); r2 += __shfl_xor(r2, 32);          \
                r3 += __shfl_xor(r3, 16); r3 += __shfl_xor(r3, 32);          \
                dst = (q == 0) ? r0 : (q == 1) ? r1 : (q == 2) ? r2 : r3;
            REDUCE_G(0, gv0)
            REDUCE_G(1, gv1)
            REDUCE_G(2, gv2)
            REDUCE_G(3, gv3)
            #undef REDUCE_G
        }
        // update: thread (bu, j)
        {
            float g0 = xv0 + gv0;
            float g1 = xv1 + gv1;
            float g2 = xv2 + gv2;
            float g3 = xv3 + gv3;
            float ig = sigmoidf_(g0), fg = sigmoidf_(g1);
            float gg = tanhf_(g2), og = sigmoidf_(g3);
            float cn = fg * c + ig * gg;
            float hn = og * tanhf_(cn);
            bool m = (teff < mylen);
            float hm = m ? hn : hreg;
            c = m ? cn : c;
            hreg = hm;
            _Float16 hh = (_Float16)hm;
            hwr[bu * 256 + j] = __builtin_bit_cast(unsigned short, hh);
            size_t orow = (size_t)(b0 + bu) * Tq + teff;
            if (OUTT == 1) ((_Float16*)out)[orow * 512 + dir * 256 + j] = (_Float16)hm;
            else           ((float*)out)[orow * 512 + dir * 256 + j] = hm;
        }
        __syncthreads();
    }
    Csav[((size_t)dir * Bq + b0 + bu) * Hq + j] = c;
    Hsav[((size_t)dir * Bq + b0 + bu) * Hq + j] = hreg;
}

extern "C" void kernel_launch(void* const* d_in, const int* in_sizes, int n_in,
                              void* d_out, int out_size, void* d_ws, size_t ws_size,
                              hipStream_t stream)
{
    const unsigned* words  = (const unsigned*)d_in[0];
    const unsigned* lens   = (const unsigned*)d_in[1];
    const float* emb     = (const float*)d_in[2];
    const float* l1f_Wih = (const float*)d_in[3];
    const float* l1f_Whh = (const float*)d_in[4];
    const float* l1f_bih = (const float*)d_in[5];
    const float* l1f_bhh = (const float*)d_in[6];
    const float* l1b_Wih = (const float*)d_in[7];
    const float* l1b_Whh = (const float*)d_in[8];
    const float* l1b_bih = (const float*)d_in[9];
    const float* l1b_bhh = (const float*)d_in[10];
    const float* l2f_Wih = (const float*)d_in[11];
    const float* l2f_Whh = (const float*)d_in[12];
    const float* l2f_bih = (const float*)d_in[13];
    const float* l2f_bhh = (const float*)d_in[14];
    const float* l2b_Wih = (const float*)d_in[15];
    const float* l2b_Whh = (const float*)d_in[16];
    const float* l2b_bih = (const float*)d_in[17];
    const float* l2b_bhh = (const float*)d_in[18];
    const float* cls_W   = (const float*)d_in[19];
    const float* cls_b   = (const float*)d_in[20];
    (void)in_sizes; (void)n_in; (void)out_size; (void)ws_size;

    char* ws = (char*)d_ws;
    size_t off = 0;
    auto alloc = [&](size_t b) { void* p = ws + off; off += (b + 255) & ~(size_t)255; return p; };
    float*     xg = (float*)alloc((size_t)Mq * 1024 * 4);   // 128 MiB, reused 4x
    float*     o1 = (float*)alloc((size_t)Mq * 512 * 4);    // 64 MiB
    _Float16*  o2 = (_Float16*)alloc((size_t)Mq * 512 * 2); // 32 MiB
    unsigned short* Wpk = (unsigned short*)alloc((size_t)8 * 131072 * 2); // 2 MiB: 4 mats x 2 planes
    float*   Hsav = (float*)alloc((size_t)2 * Bq * Hq * 4);
    float*   Csav = (float*)alloc((size_t)2 * Bq * Hq * 4);
    float* biasbuf = (float*)alloc((size_t)4 * 1024 * 4);
    unsigned* dflags = (unsigned*)alloc(256);

    const float* b1f = biasbuf, *b1b = biasbuf + 1024, *b2f = biasbuf + 2048, *b2b = biasbuf + 3072;
    unsigned short* P1fif = Wpk;
    unsigned short* P1fgo = Wpk + 131072;
    unsigned short* P1bif = Wpk + 2 * 131072;
    unsigned short* P1bgo = Wpk + 3 * 131072;
    unsigned short* P2fif = Wpk + 4 * 131072;
    unsigned short* P2fgo = Wpk + 5 * 131072;
    unsigned short* P2bif = Wpk + 6 * 131072;
    unsigned short* P2bgo = Wpk + 7 * 131072;

    const size_t ldsBytes = 65536 + 65536 + 4096;   // 135168
    hipFuncSetAttribute((const void*)lstm_shfl<0>, hipFuncAttributeMaxDynamicSharedMemorySize, (int)ldsBytes);
    hipFuncSetAttribute((const void*)lstm_shfl<1>, hipFuncAttributeMaxDynamicSharedMemorySize, (int)ldsBytes);

    detect_int64<<<1, 256, 0, stream>>>(words, lens, dflags);
    bias_kernel<<<dim3(16), 256, 0, stream>>>(l1f_bih, l1f_bhh, l1b_bih, l1b_bhh,
                                              l2f_bih, l2f_bhh, l2b_bih, l2b_bhh, biasbuf);
    pack_whh16<<<dim3(256), 256, 0, stream>>>(l1f_Whh, P1fif, P1fgo);
    pack_whh16<<<dim3(256), 256, 0, stream>>>(l1b_Whh, P1bif, P1bgo);
    pack_whh16<<<dim3(256), 256, 0, stream>>>(l2f_Whh, P2fif, P2fgo);
    pack_whh16<<<dim3(256), 256, 0, stream>>>(l2b_Whh, P2bif, P2bgo);

    dim3 ggrid(1024 / 64, Mq / 64);
    // ---- layer 1 ----
    gemm_kernel<2, 0><<<ggrid, 256, 0, stream>>>(nullptr, words, emb, dflags,
        l1f_Wih, l1b_Wih, b1f, b1b, xg, Mq, 1024, Eq);
    lstm_shfl<0><<<32, 1024, ldsBytes, stream>>>(xg, P1fif, P1fgo, P1bif, P1bgo,
        lens, dflags, Hsav, Csav, o1, 0, 256);
    gemm_kernel<2, 0><<<ggrid, 256, 0, stream>>>(nullptr, words, emb, dflags,
        l1b_Wih, l1f_Wih, b1b, b1f, xg, Mq, 1024, Eq);
    lstm_shfl<0><<<32, 1024, ldsBytes, stream>>>(xg, P1fif, P1fgo, P1bif, P1bgo,
        lens, dflags, Hsav, Csav, o1, 256, 512);
    // ---- layer 2 ----
    gemm_kernel<0, 0><<<ggrid, 256, 0, stream>>>(o1, nullptr, nullptr, dflags,
        l2f_Wih, l2b_Wih, b2f, b2b, xg, Mq, 1024, 512);
    lstm_shfl<1><<<32, 1024, ldsBytes, stream>>>(xg, P2fif, P2fgo, P2bif, P2bgo,
        lens, dflags, Hsav, Csav, o2, 0, 256);
    gemm_kernel<0, 0><<<ggrid, 256, 0, stream>>>(o1, nullptr, nullptr, dflags,
        l2b_Wih, l2f_Wih, b2b, b2f, xg, Mq, 1024, 512);
    lstm_shfl<1><<<32, 1024, ldsBytes, stream>>>(xg, P2fif, P2fgo, P2bif, P2bgo,
        lens, dflags, Hsav, Csav, o2, 256, 512);
    // ---- classifier -> d_out (f32) ----
    gemm_kernel<3, 0><<<dim3(1, Mq / 64), 256, 0, stream>>>(o2, nullptr, nullptr, dflags,
        cls_W, cls_W, cls_b, cls_b, d_out, Mq, NTAGS, 512);
}

// Round 18
// 5063.785 us; speedup vs baseline: 1.9339x; 1.4739x over previous
//
#include <hip/hip_runtime.h>
#include <hip/hip_bf16.h>

#define Bq 64
#define Tq 512
#define Eq 128
#define Hq 256
#define NTAGS 50
#define Mq (Bq*Tq)   // 32768

typedef _Float16 v8hf __attribute__((ext_vector_type(8)));
typedef float v4f __attribute__((ext_vector_type(4)));

__device__ __forceinline__ float sigmoidf_(float x) { return 1.f / (1.f + __expf(-x)); }
__device__ __forceinline__ float tanhf_(float x) {
    float e = __expf(2.f * x);
    return 1.f - 2.f / (e + 1.f);
}

// ---------------- dtype detection: int32 vs int64 for words/lengths ----------------
__global__ void detect_int64(const unsigned* __restrict__ words,
                             const unsigned* __restrict__ lens,
                             unsigned* __restrict__ dflags) {
    __shared__ int wbad, lbad, wnz, lnz;
    if (threadIdx.x == 0) { wbad = 0; lbad = 0; wnz = 0; lnz = 0; }
    __syncthreads();
    for (int i = threadIdx.x; i < 16384; i += blockDim.x) {
        if (words[2 * i + 1] != 0u) wbad = 1;
        if (words[2 * i] != 0u) wnz = 1;
    }
    for (int i = threadIdx.x; i < 32; i += blockDim.x) {
        if (lens[2 * i + 1] != 0u) lbad = 1;
        if (lens[2 * i] != 0u) lnz = 1;
    }
    __syncthreads();
    if (threadIdx.x == 0) {
        unsigned f = 0;
        if (!wbad && wnz) f |= 1u;
        if (!lbad && lnz) f |= 2u;
        dflags[0] = f;
    }
}

// ---------------- bias: bias[l][d][n] = bih + bhh ----------------
__global__ void bias_kernel(const float* b1f_ih, const float* b1f_hh,
                            const float* b1b_ih, const float* b1b_hh,
                            const float* b2f_ih, const float* b2f_hh,
                            const float* b2b_ih, const float* b2b_hh,
                            float* bias) {   // [4][1024]: l1f,l1b,l2f,l2b
    int i = blockIdx.x * blockDim.x + threadIdx.x;
    if (i >= 4096) return;
    int l = i >> 11, d = (i >> 10) & 1, nn = i & 1023;
    float v;
    if (l == 0) v = d ? (b1b_ih[nn] + b1b_hh[nn]) : (b1f_ih[nn] + b1f_hh[nn]);
    else        v = d ? (b2b_ih[nn] + b2b_hh[nn]) : (b2f_ih[nn] + b2f_hh[nn]);
    bias[i] = v;
}

// ---------------- Whh -> MFMA A-fragment packing ----------------
// frag fg = w*32 + mtl*8 + kc  (w=wave 0..15, mtl=M-tile-local 0..3, kc=K-chunk 0..7)
// lane holds A[grow = (w*4+mtl)*16 + (lane&15)][k = kc*32 + (lane>>4)*8 + i], i=0..7
// stored as PA[(fg*64+lane)*8 + i] (f16) -> per-frag wave load = 64 x 16B contiguous.
__global__ void pack_whh_mfma(const float* __restrict__ W, _Float16* __restrict__ PA) {
    int t = blockIdx.x * 256 + threadIdx.x;   // chunk id 0..32767
    if (t >= 32768) return;
    int fg = t >> 6, lane = t & 63;
    int w = fg >> 5, rem = fg & 31, mtl = rem >> 3, kc = rem & 7;
    int grow = (w * 4 + mtl) * 16 + (lane & 15);
    int kb = kc * 32 + (lane >> 4) * 8;
    _Float16 h8[8];
    #pragma unroll
    for (int i = 0; i < 8; ++i) h8[i] = (_Float16)W[(size_t)grow * 256 + kb + i];
    *(uint4*)(PA + ((size_t)fg * 64 + lane) * 8) = *(const uint4*)h8;
}

// ---------------- f32 GEMM: C[M,N] = A[M,K] @ W[N,K]^T + bias (unchanged, passing) ----------------
template<int AMODE, int OUTT>
__global__ __launch_bounds__(256)
void gemm_kernel(const void* __restrict__ Aptr, const unsigned* __restrict__ words_u32,
                 const float* __restrict__ emb, const unsigned* __restrict__ dflags,
                 const float* __restrict__ Wlo, const float* __restrict__ Whi,
                 const float* __restrict__ blo, const float* __restrict__ bhi,
                 void* __restrict__ Cptr, int M, int N, int K)
{
    __shared__ float As[16][68];
    __shared__ float Ws[16][68];
    const int tx = threadIdx.x & 15, ty = threadIdx.x >> 4;
    const int m0 = blockIdx.y * 64, n0 = blockIdx.x * 64;
    const bool hi = ((m0 & 511) >= 256);
    const float* W = hi ? Whi : Wlo;
    const float* bias = hi ? bhi : blo;
    const int lr = threadIdx.x >> 2, lc = threadIdx.x & 3;
    bool w64 = false;
    if (AMODE == 2) w64 = (dflags[0] & 1u) != 0u;
    float acc[4][4] = {};
    for (int k0 = 0; k0 < K; k0 += 16) {
        float a4[4], w4[4];
        if (AMODE == 2) {
            int m = m0 + lr;
            int w = (int)(w64 ? words_u32[2 * m] : words_u32[m]);
            float4 v = *(const float4*)(emb + (size_t)w * Eq + k0 + lc * 4);
            a4[0] = v.x; a4[1] = v.y; a4[2] = v.z; a4[3] = v.w;
        } else if (AMODE == 0) {
            float4 v = *(const float4*)((const float*)Aptr + (size_t)(m0 + lr) * K + k0 + lc * 4);
            a4[0] = v.x; a4[1] = v.y; a4[2] = v.z; a4[3] = v.w;
        } else {
            const _Float16* Ab = (const _Float16*)Aptr + (size_t)(m0 + lr) * K + k0 + lc * 4;
            #pragma unroll
            for (int q = 0; q < 4; ++q) a4[q] = (float)Ab[q];
        }
        int nrow = n0 + lr;
        if (nrow < N) {
            float4 v = *(const float4*)(W + (size_t)nrow * K + k0 + lc * 4);
            w4[0] = v.x; w4[1] = v.y; w4[2] = v.z; w4[3] = v.w;
        } else { w4[0] = w4[1] = w4[2] = w4[3] = 0.f; }
        __syncthreads();
        #pragma unroll
        for (int q = 0; q < 4; ++q) {
            As[lc * 4 + q][lr] = a4[q];
            Ws[lc * 4 + q][lr] = w4[q];
        }
        __syncthreads();
        #pragma unroll
        for (int kk = 0; kk < 16; ++kk) {
            float4 a = *(const float4*)&As[kk][ty * 4];
            float4 w = *(const float4*)&Ws[kk][tx * 4];
            float av[4] = {a.x, a.y, a.z, a.w};
            float wv[4] = {w.x, w.y, w.z, w.w};
            #pragma unroll
            for (int i = 0; i < 4; ++i)
                #pragma unroll
                for (int j = 0; j < 4; ++j)
                    acc[i][j] += av[i] * wv[j];
        }
    }
    #pragma unroll
    for (int i = 0; i < 4; ++i) {
        int row = m0 + ty * 4 + i;
        #pragma unroll
        for (int j = 0; j < 4; ++j) {
            int col = n0 + tx * 4 + j;
            if (col < N) {
                float v = acc[i][j] + bias[col];
                if (OUTT == 1) ((_Float16*)Cptr)[(size_t)row * N + col] = (_Float16)v;
                else           ((float*)Cptr)[(size_t)row * N + col] = v;
            }
        }
    }
}

// ---------------- MFMA LSTM: gates = W @ h via mfma_f32_16x16x32_f16 ----------------
// 32 blocks x 1024 threads (16 waves). Wave w owns gate-rows [w*64, w*64+64)
// as 4 M-tiles x 8 K-chunks. A(W)-frags: regs kc0-3 of mtl0 + LDS mtl1 + stream rest.
// B(h)-frags: lane n=lane&15 -> batch (n<4 real, else zero); k=(lane>>4)*8+i from
// parity-buffered f16 h. D: col=lane&15 -> batch, row=(lane>>4)*4+reg (HW-verified).
// D -> LDS gate buffer -> update threads (bu=tid>>8, j=tid&255). 2 barriers/step.
// OUTT: 0 = f32, 1 = f16
template<int OUTT>
__global__ __launch_bounds__(1024)
void lstm_mfma(const float* __restrict__ xg,      // [M][1024] phased
               const _Float16* __restrict__ PAf, const _Float16* __restrict__ PAb,
               const unsigned* __restrict__ len_u32,
               const unsigned* __restrict__ dflags,
               float* __restrict__ Hsav,          // [2][Bq][Hq]
               float* __restrict__ Csav,          // [2][Bq][Hq]
               void* __restrict__ out,            // [M][512]
               int t0, int t1)
{
    extern __shared__ char lds_raw[];
    _Float16* ldsA = (_Float16*)lds_raw;                       // 128KB: [128][64][8]
    float*    gbuf = (float*)(lds_raw + 131072);               // [4][1032] f32 = 16512B
    _Float16* h16  = (_Float16*)(lds_raw + 131072 + 16512);    // [2][4][264] = 4224B

    const int tid = threadIdx.x;
    const int bid = blockIdx.x;
    const int dir = bid >> 4;
    const int b0  = (bid & 15) * 4;
    const int w    = tid >> 6;
    const int lane = tid & 63;
    const int n    = lane & 15;
    const int kg   = lane >> 4;
    const int bu   = tid >> 8;       // update batch
    const int j    = tid & 255;      // update unit
    const _Float16* __restrict__ PA = dir ? PAb : PAf;
    const bool l64 = (dflags[0] & 2u) != 0u;
    const int mylen = (int)(l64 ? len_u32[2 * (b0 + bu)] : len_u32[b0 + bu]);

    // stage mtl1 A-frags into LDS: lfrag = w_s*8 + kc_s  (128 frags x 1KB)
    for (int chunk = tid; chunk < 8192; chunk += 1024) {
        int lfrag = chunk >> 6, lane_s = chunk & 63;
        int w_s = lfrag >> 3, kc_s = lfrag & 7;
        int fg = w_s * 32 + 8 + kc_s;
        *(uint4*)(ldsA + (size_t)chunk * 8) = *(const uint4*)(PA + ((size_t)fg * 64 + lane_s) * 8);
    }
    // reg A-frags: mtl0, kc 0..3 (16 VGPR — round-14-proven size)
    uint4 Ar[4];
    #pragma unroll
    for (int kc = 0; kc < 4; ++kc)
        Ar[kc] = *(const uint4*)(PA + ((size_t)(w * 32 + kc) * 64 + lane) * 8);

    float c = 0.f, hreg;
    {
        if (t0 == 0) {
            hreg = 0.f;
        } else {
            c    = Csav[((size_t)dir * Bq + b0 + bu) * Hq + j];
            hreg = Hsav[((size_t)dir * Bq + b0 + bu) * Hq + j];
        }
        _Float16 hh = (_Float16)hreg;
        h16[(t0 & 1) * 1056 + bu * 264 + j] = hh;
    }
    __syncthreads();

    for (int t = t0; t < t1; ++t) {
        const int teff = dir ? (Tq - 1 - t) : t;
        const int par = t & 1;
        const _Float16* hrd = h16 + par * 1056;

        const float* xr = xg + ((size_t)(b0 + bu) * Tq + teff) * 1024 + j;
        float xv0 = xr[0], xv1 = xr[256], xv2 = xr[512], xv3 = xr[768];

        v4f acc0 = {0.f, 0.f, 0.f, 0.f};
        v4f acc1 = {0.f, 0.f, 0.f, 0.f};
        v4f acc2 = {0.f, 0.f, 0.f, 0.f};
        v4f acc3 = {0.f, 0.f, 0.f, 0.f};
        #pragma unroll
        for (int kc = 0; kc < 8; ++kc) {
            // B(h) fragment: batch n (zero for pad lanes), k = kc*32 + kg*8 + i
            v8hf B;
            if (n < 4) {
                uint4 hb = *(const uint4*)(hrd + n * 264 + kc * 32 + kg * 8);
                B = __builtin_bit_cast(v8hf, hb);
            } else {
                uint4 z = {0u, 0u, 0u, 0u};
                B = __builtin_bit_cast(v8hf, z);
            }
            // mtl0: regs (kc<4) or streamed
            v8hf A0;
            if (kc < 4) A0 = __builtin_bit_cast(v8hf, Ar[kc]);
            else A0 = __builtin_bit_cast(v8hf, *(const uint4*)(PA + ((size_t)(w * 32 + kc) * 64 + lane) * 8));
            acc0 = __builtin_amdgcn_mfma_f32_16x16x32_f16(A0, B, acc0, 0, 0, 0);
            // mtl1: LDS
            v8hf A1 = __builtin_bit_cast(v8hf, *(const uint4*)(ldsA + ((size_t)(w * 8 + kc) * 64 + lane) * 8));
            acc1 = __builtin_amdgcn_mfma_f32_16x16x32_f16(A1, B, acc1, 0, 0, 0);
            // mtl2, mtl3: streamed
            v8hf A2 = __builtin_bit_cast(v8hf, *(const uint4*)(PA + ((size_t)(w * 32 + 16 + kc) * 64 + lane) * 8));
            acc2 = __builtin_amdgcn_mfma_f32_16x16x32_f16(A2, B, acc2, 0, 0, 0);
            v8hf A3 = __builtin_bit_cast(v8hf, *(const uint4*)(PA + ((size_t)(w * 32 + 24 + kc) * 64 + lane) * 8));
            acc3 = __builtin_amdgcn_mfma_f32_16x16x32_f16(A3, B, acc3, 0, 0, 0);
        }
        // D -> gate buffer: lane holds (batch n, rows kg*4+r of its M-tiles)
        if (n < 4) {
            float* gp = gbuf + n * 1032 + w * 64 + kg * 4;
            gp[0]  = acc0[0]; gp[1]  = acc0[1]; gp[2]  = acc0[2]; gp[3]  = acc0[3];
            gp[16] = acc1[0]; gp[17] = acc1[1]; gp[18] = acc1[2]; gp[19] = acc1[3];
            gp[32] = acc2[0]; gp[33] = acc2[1]; gp[34] = acc2[2]; gp[35] = acc2[3];
            gp[48] = acc3[0]; gp[49] = acc3[1]; gp[50] = acc3[2]; gp[51] = acc3[3];
        }
        __syncthreads();
        // update: thread (bu, j)
        {
            float g0 = xv0 + gbuf[bu * 1032 + 0 * 256 + j];
            float g1 = xv1 + gbuf[bu * 1032 + 1 * 256 + j];
            float g2 = xv2 + gbuf[bu * 1032 + 2 * 256 + j];
            float g3 = xv3 + gbuf[bu * 1032 + 3 * 256 + j];
            float ig = sigmoidf_(g0), fg = sigmoidf_(g1);
            float gg = tanhf_(g2), og = sigmoidf_(g3);
            float cn = fg * c + ig * gg;
            float hn = og * tanhf_(cn);
            bool m = (teff < mylen);
            float hm = m ? hn : hreg;
            c = m ? cn : c;
            hreg = hm;
            h16[(par ^ 1) * 1056 + bu * 264 + j] = (_Float16)hm;
            size_t orow = (size_t)(b0 + bu) * Tq + teff;
            if (OUTT == 1) ((_Float16*)out)[orow * 512 + dir * 256 + j] = (_Float16)hm;
            else           ((float*)out)[orow * 512 + dir * 256 + j] = hm;
        }
        __syncthreads();
    }
    Csav[((size_t)dir * Bq + b0 + bu) * Hq + j] = c;
    Hsav[((size_t)dir * Bq + b0 + bu) * Hq + j] = hreg;
}

extern "C" void kernel_launch(void* const* d_in, const int* in_sizes, int n_in,
                              void* d_out, int out_size, void* d_ws, size_t ws_size,
                              hipStream_t stream)
{
    const unsigned* words  = (const unsigned*)d_in[0];
    const unsigned* lens   = (const unsigned*)d_in[1];
    const float* emb     = (const float*)d_in[2];
    const float* l1f_Wih = (const float*)d_in[3];
    const float* l1f_Whh = (const float*)d_in[4];
    const float* l1f_bih = (const float*)d_in[5];
    const float* l1f_bhh = (const float*)d_in[6];
    const float* l1b_Wih = (const float*)d_in[7];
    const float* l1b_Whh = (const float*)d_in[8];
    const float* l1b_bih = (const float*)d_in[9];
    const float* l1b_bhh = (const float*)d_in[10];
    const float* l2f_Wih = (const float*)d_in[11];
    const float* l2f_Whh = (const float*)d_in[12];
    const float* l2f_bih = (const float*)d_in[13];
    const float* l2f_bhh = (const float*)d_in[14];
    const float* l2b_Wih = (const float*)d_in[15];
    const float* l2b_Whh = (const float*)d_in[16];
    const float* l2b_bih = (const float*)d_in[17];
    const float* l2b_bhh = (const float*)d_in[18];
    const float* cls_W   = (const float*)d_in[19];
    const float* cls_b   = (const float*)d_in[20];
    (void)in_sizes; (void)n_in; (void)out_size; (void)ws_size;

    char* ws = (char*)d_ws;
    size_t off = 0;
    auto alloc = [&](size_t b) { void* p = ws + off; off += (b + 255) & ~(size_t)255; return p; };
    float*     xg = (float*)alloc((size_t)Mq * 1024 * 4);   // 128 MiB, reused 4x
    float*     o1 = (float*)alloc((size_t)Mq * 512 * 4);    // 64 MiB
    _Float16*  o2 = (_Float16*)alloc((size_t)Mq * 512 * 2); // 32 MiB
    _Float16* PAk = (_Float16*)alloc((size_t)4 * 262144 * 2); // 2 MiB: 4 matrices in frag layout
    float*   Hsav = (float*)alloc((size_t)2 * Bq * Hq * 4);
    float*   Csav = (float*)alloc((size_t)2 * Bq * Hq * 4);
    float* biasbuf = (float*)alloc((size_t)4 * 1024 * 4);
    unsigned* dflags = (unsigned*)alloc(256);

    const float* b1f = biasbuf, *b1b = biasbuf + 1024, *b2f = biasbuf + 2048, *b2b = biasbuf + 3072;
    _Float16* PA1f = PAk;
    _Float16* PA1b = PAk + 262144;
    _Float16* PA2f = PAk + 2 * 262144;
    _Float16* PA2b = PAk + 3 * 262144;

    const size_t ldsBytes = 131072 + 16512 + 4224;   // 151808
    hipFuncSetAttribute((const void*)lstm_mfma<0>, hipFuncAttributeMaxDynamicSharedMemorySize, (int)ldsBytes);
    hipFuncSetAttribute((const void*)lstm_mfma<1>, hipFuncAttributeMaxDynamicSharedMemorySize, (int)ldsBytes);

    detect_int64<<<1, 256, 0, stream>>>(words, lens, dflags);
    bias_kernel<<<dim3(16), 256, 0, stream>>>(l1f_bih, l1f_bhh, l1b_bih, l1b_bhh,
                                              l2f_bih, l2f_bhh, l2b_bih, l2b_bhh, biasbuf);
    pack_whh_mfma<<<dim3(128), 256, 0, stream>>>(l1f_Whh, PA1f);
    pack_whh_mfma<<<dim3(128), 256, 0, stream>>>(l1b_Whh, PA1b);
    pack_whh_mfma<<<dim3(128), 256, 0, stream>>>(l2f_Whh, PA2f);
    pack_whh_mfma<<<dim3(128), 256, 0, stream>>>(l2b_Whh, PA2b);

    dim3 ggrid(1024 / 64, Mq / 64);
    // ---- layer 1 ----
    gemm_kernel<2, 0><<<ggrid, 256, 0, stream>>>(nullptr, words, emb, dflags,
        l1f_Wih, l1b_Wih, b1f, b1b, xg, Mq, 1024, Eq);
    lstm_mfma<0><<<32, 1024, ldsBytes, stream>>>(xg, PA1f, PA1b, lens, dflags, Hsav, Csav, o1, 0, 256);
    gemm_kernel<2, 0><<<ggrid, 256, 0, stream>>>(nullptr, words, emb, dflags,
        l1b_Wih, l1f_Wih, b1b, b1f, xg, Mq, 1024, Eq);
    lstm_mfma<0><<<32, 1024, ldsBytes, stream>>>(xg, PA1f, PA1b, lens, dflags, Hsav, Csav, o1, 256, 512);
    // ---- layer 2 ----
    gemm_kernel<0, 0><<<ggrid, 256, 0, stream>>>(o1, nullptr, nullptr, dflags,
        l2f_Wih, l2b_Wih, b2f, b2b, xg, Mq, 1024, 512);
    lstm_mfma<1><<<32, 1024, ldsBytes, stream>>>(xg, PA2f, PA2b, lens, dflags, Hsav, Csav, o2, 0, 256);
    gemm_kernel<0, 0><<<ggrid, 256, 0, stream>>>(o1, nullptr, nullptr, dflags,
        l2b_Wih, l2f_Wih, b2b, b2f, xg, Mq, 1024, 512);
    lstm_mfma<1><<<32, 1024, ldsBytes, stream>>>(xg, PA2f, PA2b, lens, dflags, Hsav, Csav, o2, 256, 512);
    // ---- classifier -> d_out (f32) ----
    gemm_kernel<3, 0><<<dim3(1, Mq / 64), 256, 0, stream>>>(o2, nullptr, nullptr, dflags,
        cls_W, cls_W, cls_b, cls_b, d_out, Mq, NTAGS, 512);
}

// Round 19
// 3811.187 us; speedup vs baseline: 2.5695x; 1.3287x over previous
//
#include <hip/hip_runtime.h>
#include <hip/hip_bf16.h>

#define Bq 64
#define Tq 512
#define Eq 128
#define Hq 256
#define NTAGS 50
#define Mq (Bq*Tq)   // 32768

typedef _Float16 v8hf __attribute__((ext_vector_type(8)));
typedef float v4f __attribute__((ext_vector_type(4)));

__device__ __forceinline__ float sigmoidf_(float x) { return 1.f / (1.f + __expf(-x)); }
__device__ __forceinline__ float tanhf_(float x) {
    float e = __expf(2.f * x);
    return 1.f - 2.f / (e + 1.f);
}

// ---------------- dtype detection: int32 vs int64 for words/lengths ----------------
__global__ void detect_int64(const unsigned* __restrict__ words,
                             const unsigned* __restrict__ lens,
                             unsigned* __restrict__ dflags) {
    __shared__ int wbad, lbad, wnz, lnz;
    if (threadIdx.x == 0) { wbad = 0; lbad = 0; wnz = 0; lnz = 0; }
    __syncthreads();
    for (int i = threadIdx.x; i < 16384; i += blockDim.x) {
        if (words[2 * i + 1] != 0u) wbad = 1;
        if (words[2 * i] != 0u) wnz = 1;
    }
    for (int i = threadIdx.x; i < 32; i += blockDim.x) {
        if (lens[2 * i + 1] != 0u) lbad = 1;
        if (lens[2 * i] != 0u) lnz = 1;
    }
    __syncthreads();
    if (threadIdx.x == 0) {
        unsigned f = 0;
        if (!wbad && wnz) f |= 1u;
        if (!lbad && lnz) f |= 2u;
        dflags[0] = f;
    }
}

// ---------------- bias: bias[l][d][n] = bih + bhh ----------------
__global__ void bias_kernel(const float* b1f_ih, const float* b1f_hh,
                            const float* b1b_ih, const float* b1b_hh,
                            const float* b2f_ih, const float* b2f_hh,
                            const float* b2b_ih, const float* b2b_hh,
                            float* bias) {   // [4][1024]: l1f,l1b,l2f,l2b
    int i = blockIdx.x * blockDim.x + threadIdx.x;
    if (i >= 4096) return;
    int l = i >> 11, d = (i >> 10) & 1, nn = i & 1023;
    float v;
    if (l == 0) v = d ? (b1b_ih[nn] + b1b_hh[nn]) : (b1f_ih[nn] + b1f_hh[nn]);
    else        v = d ? (b2b_ih[nn] + b2b_hh[nn]) : (b2f_ih[nn] + b2f_hh[nn]);
    bias[i] = v;
}

// ---------------- Whh -> MFMA A-fragment packing (verified round 18) ----------------
__global__ void pack_whh_mfma(const float* __restrict__ W, _Float16* __restrict__ PA) {
    int t = blockIdx.x * 256 + threadIdx.x;   // chunk id 0..32767
    if (t >= 32768) return;
    int fg = t >> 6, lane = t & 63;
    int w = fg >> 5, rem = fg & 31, mtl = rem >> 3, kc = rem & 7;
    int grow = (w * 4 + mtl) * 16 + (lane & 15);
    int kb = kc * 32 + (lane >> 4) * 8;
    _Float16 h8[8];
    #pragma unroll
    for (int i = 0; i < 8; ++i) h8[i] = (_Float16)W[(size_t)grow * 256 + kb + i];
    *(uint4*)(PA + ((size_t)fg * 64 + lane) * 8) = *(const uint4*)h8;
}

// ---------------- generic W[N][K] f32 -> MFMA B-fragment packing ----------------
// frag fg = ntile*(K/32) + kc ; lane: n = ntile*16 + (lane&15), k = kc*32+(lane>>4)*8+i
// rows n >= Nvalid are zero. Chunks total = (Npad/16)*(K/32)*64.
__global__ void pack_w_bfrag(const float* __restrict__ W, _Float16* __restrict__ PB,
                             int Nvalid, int K, int nchunks) {
    int t = blockIdx.x * 256 + threadIdx.x;
    if (t >= nchunks) return;
    int fg = t >> 6, lane = t & 63;
    int kcn = K >> 5;
    int ntile = fg / kcn, kc = fg % kcn;
    int n = ntile * 16 + (lane & 15);
    int kb = kc * 32 + (lane >> 4) * 8;
    _Float16 h8[8];
    #pragma unroll
    for (int i = 0; i < 8; ++i)
        h8[i] = (n < Nvalid) ? (_Float16)W[(size_t)n * K + kb + i] : (_Float16)0.f;
    *(uint4*)(PB + ((size_t)fg * 64 + lane) * 8) = *(const uint4*)h8;
}

// ---------------- MFMA GEMM: C[M, Nstr] = A[M,K] @ W^T + bias ----------------
// 256 threads = 4 waves; block tile 64(M) x 256(N); wave w -> cols [w*64, w*64+64).
// A staged in LDS [64][40] f16 (padded, 16B-aligned, <=2-way conflicts).
// B from pre-packed f16 fragments (L2-resident). Fragment conventions verified
// in round-18 lstm_mfma. AMODE: 0 = A f16 buffer, 2 = emb gather (f32->f16).
// OUTT: 1 = f16 store at stride Nstr; 0 = f32 store at stride Nstr, cols < Nvalid only.
template<int AMODE, int OUTT>
__global__ __launch_bounds__(256)
void gemm_mfma(const _Float16* __restrict__ Asrc, const unsigned* __restrict__ words_u32,
               const float* __restrict__ emb, const unsigned* __restrict__ dflags,
               const _Float16* __restrict__ PB, const float* __restrict__ bias,
               void* __restrict__ Cptr, int Nstr, int K, int Nvalid)
{
    __shared__ _Float16 At[64 * 40];
    const int tid = threadIdx.x;
    const int w = tid >> 6, lane = tid & 63;
    const int n0w = blockIdx.x * 256 + w * 64;
    const int m0 = blockIdx.y * 64;
    const int srow = tid >> 2, sseg = tid & 3;
    const int kcn = K >> 5;
    const int ntb = n0w >> 4;           // wave's base n-tile
    bool w64 = false;
    if (AMODE == 2) w64 = (dflags[0] & 1u) != 0u;

    v4f acc[4][4] = {};
    for (int kc0 = 0; kc0 < kcn; ++kc0) {
        // stage A[64][32] -> LDS (f16, padded rows of 40)
        if (AMODE == 0) {
            uint4 v = *(const uint4*)(Asrc + (size_t)(m0 + srow) * K + kc0 * 32 + sseg * 8);
            *(uint4*)(At + srow * 40 + sseg * 8) = v;
        } else {
            int wd = (int)(w64 ? words_u32[2 * (m0 + srow)] : words_u32[m0 + srow]);
            const float* src = emb + (size_t)wd * Eq + kc0 * 32 + sseg * 8;
            float4 v0 = *(const float4*)src;
            float4 v1 = *(const float4*)(src + 4);
            _Float16 h8[8] = {(_Float16)v0.x, (_Float16)v0.y, (_Float16)v0.z, (_Float16)v0.w,
                              (_Float16)v1.x, (_Float16)v1.y, (_Float16)v1.z, (_Float16)v1.w};
            *(uint4*)(At + srow * 40 + sseg * 8) = *(const uint4*)h8;
        }
        __syncthreads();
        // B fragments (global, coalesced 1KB/wave) and A fragments (LDS)
        v8hf Bf[4];
        #pragma unroll
        for (int nf = 0; nf < 4; ++nf) {
            size_t fg = (size_t)(ntb + nf) * kcn + kc0;
            Bf[nf] = __builtin_bit_cast(v8hf, *(const uint4*)(PB + (fg * 64 + lane) * 8));
        }
        #pragma unroll
        for (int mf = 0; mf < 4; ++mf) {
            v8hf Af = __builtin_bit_cast(v8hf,
                *(const uint4*)(At + (mf * 16 + (lane & 15)) * 40 + (lane >> 4) * 8));
            #pragma unroll
            for (int nf = 0; nf < 4; ++nf)
                acc[mf][nf] = __builtin_amdgcn_mfma_f32_16x16x32_f16(Af, Bf[nf], acc[mf][nf], 0, 0, 0);
        }
        __syncthreads();
    }
    // epilogue: D col = lane&15, row = (lane>>4)*4 + r  (verified mapping)
    #pragma unroll
    for (int nf = 0; nf < 4; ++nf) {
        int colb = n0w + nf * 16 + (lane & 15);
        float bb = (colb < Nvalid) ? bias[colb] : 0.f;
        #pragma unroll
        for (int mf = 0; mf < 4; ++mf) {
            int rowb = m0 + mf * 16 + (lane >> 4) * 4;
            #pragma unroll
            for (int r = 0; r < 4; ++r) {
                float v = acc[mf][nf][r] + bb;
                if (OUTT == 1) {
                    ((_Float16*)Cptr)[(size_t)(rowb + r) * Nstr + colb] = (_Float16)v;
                } else {
                    if (colb < Nvalid)
                        ((float*)Cptr)[(size_t)(rowb + r) * Nstr + colb] = v;
                }
            }
        }
    }
}

// ---------------- MFMA LSTM (round-18 verified), xg f16 full-width, single phase ----------------
__global__ __launch_bounds__(1024)
void lstm_mfma(const _Float16* __restrict__ xg,   // [M][2048] f16, col = dir*1024+g*256+j
               const _Float16* __restrict__ PAf, const _Float16* __restrict__ PAb,
               const unsigned* __restrict__ len_u32,
               const unsigned* __restrict__ dflags,
               _Float16* __restrict__ out)        // [M][512] f16
{
    extern __shared__ char lds_raw[];
    _Float16* ldsA = (_Float16*)lds_raw;                       // 128KB: [128][64][8]
    float*    gbuf = (float*)(lds_raw + 131072);               // [4][1032] f32 = 16512B
    _Float16* h16  = (_Float16*)(lds_raw + 131072 + 16512);    // [2][4][264] = 4224B

    const int tid = threadIdx.x;
    const int bid = blockIdx.x;
    const int dir = bid >> 4;
    const int b0  = (bid & 15) * 4;
    const int w    = tid >> 6;
    const int lane = tid & 63;
    const int n    = lane & 15;
    const int kg   = lane >> 4;
    const int bu   = tid >> 8;
    const int j    = tid & 255;
    const _Float16* __restrict__ PA = dir ? PAb : PAf;
    const bool l64 = (dflags[0] & 2u) != 0u;
    const int mylen = (int)(l64 ? len_u32[2 * (b0 + bu)] : len_u32[b0 + bu]);

    for (int chunk = tid; chunk < 8192; chunk += 1024) {
        int lfrag = chunk >> 6, lane_s = chunk & 63;
        int w_s = lfrag >> 3, kc_s = lfrag & 7;
        int fg = w_s * 32 + 8 + kc_s;
        *(uint4*)(ldsA + (size_t)chunk * 8) = *(const uint4*)(PA + ((size_t)fg * 64 + lane_s) * 8);
    }
    uint4 Ar[4];
    #pragma unroll
    for (int kc = 0; kc < 4; ++kc)
        Ar[kc] = *(const uint4*)(PA + ((size_t)(w * 32 + kc) * 64 + lane) * 8);

    float c = 0.f, hreg = 0.f;
    h16[0 * 1056 + bu * 264 + j] = (_Float16)0.f;
    __syncthreads();

    for (int t = 0; t < Tq; ++t) {
        const int teff = dir ? (Tq - 1 - t) : t;
        const int par = t & 1;
        const _Float16* hrd = h16 + par * 1056;

        const _Float16* xr = xg + ((size_t)(b0 + bu) * Tq + teff) * 2048 + dir * 1024 + j;
        float xv0 = (float)xr[0], xv1 = (float)xr[256], xv2 = (float)xr[512], xv3 = (float)xr[768];

        v4f acc0 = {0.f, 0.f, 0.f, 0.f};
        v4f acc1 = {0.f, 0.f, 0.f, 0.f};
        v4f acc2 = {0.f, 0.f, 0.f, 0.f};
        v4f acc3 = {0.f, 0.f, 0.f, 0.f};
        #pragma unroll
        for (int kc = 0; kc < 8; ++kc) {
            v8hf B;
            if (n < 4) {
                uint4 hb = *(const uint4*)(hrd + n * 264 + kc * 32 + kg * 8);
                B = __builtin_bit_cast(v8hf, hb);
            } else {
                uint4 z = {0u, 0u, 0u, 0u};
                B = __builtin_bit_cast(v8hf, z);
            }
            v8hf A0;
            if (kc < 4) A0 = __builtin_bit_cast(v8hf, Ar[kc]);
            else A0 = __builtin_bit_cast(v8hf, *(const uint4*)(PA + ((size_t)(w * 32 + kc) * 64 + lane) * 8));
            acc0 = __builtin_amdgcn_mfma_f32_16x16x32_f16(A0, B, acc0, 0, 0, 0);
            v8hf A1 = __builtin_bit_cast(v8hf, *(const uint4*)(ldsA + ((size_t)(w * 8 + kc) * 64 + lane) * 8));
            acc1 = __builtin_amdgcn_mfma_f32_16x16x32_f16(A1, B, acc1, 0, 0, 0);
            v8hf A2 = __builtin_bit_cast(v8hf, *(const uint4*)(PA + ((size_t)(w * 32 + 16 + kc) * 64 + lane) * 8));
            acc2 = __builtin_amdgcn_mfma_f32_16x16x32_f16(A2, B, acc2, 0, 0, 0);
            v8hf A3 = __builtin_bit_cast(v8hf, *(const uint4*)(PA + ((size_t)(w * 32 + 24 + kc) * 64 + lane) * 8));
            acc3 = __builtin_amdgcn_mfma_f32_16x16x32_f16(A3, B, acc3, 0, 0, 0);
        }
        if (n < 4) {
            float* gp = gbuf + n * 1032 + w * 64 + kg * 4;
            gp[0]  = acc0[0]; gp[1]  = acc0[1]; gp[2]  = acc0[2]; gp[3]  = acc0[3];
            gp[16] = acc1[0]; gp[17] = acc1[1]; gp[18] = acc1[2]; gp[19] = acc1[3];
            gp[32] = acc2[0]; gp[33] = acc2[1]; gp[34] = acc2[2]; gp[35] = acc2[3];
            gp[48] = acc3[0]; gp[49] = acc3[1]; gp[50] = acc3[2]; gp[51] = acc3[3];
        }
        __syncthreads();
        {
            float g0 = xv0 + gbuf[bu * 1032 + 0 * 256 + j];
            float g1 = xv1 + gbuf[bu * 1032 + 1 * 256 + j];
            float g2 = xv2 + gbuf[bu * 1032 + 2 * 256 + j];
            float g3 = xv3 + gbuf[bu * 1032 + 3 * 256 + j];
            float ig = sigmoidf_(g0), fg = sigmoidf_(g1);
            float gg = tanhf_(g2), og = sigmoidf_(g3);
            float cn = fg * c + ig * gg;
            float hn = og * tanhf_(cn);
            bool m = (teff < mylen);
            float hm = m ? hn : hreg;
            c = m ? cn : c;
            hreg = hm;
            h16[(par ^ 1) * 1056 + bu * 264 + j] = (_Float16)hm;
            size_t orow = (size_t)(b0 + bu) * Tq + teff;
            out[orow * 512 + dir * 256 + j] = (_Float16)hm;
        }
        __syncthreads();
    }
}

extern "C" void kernel_launch(void* const* d_in, const int* in_sizes, int n_in,
                              void* d_out, int out_size, void* d_ws, size_t ws_size,
                              hipStream_t stream)
{
    const unsigned* words  = (const unsigned*)d_in[0];
    const unsigned* lens   = (const unsigned*)d_in[1];
    const float* emb     = (const float*)d_in[2];
    const float* l1f_Wih = (const float*)d_in[3];
    const float* l1f_Whh = (const float*)d_in[4];
    const float* l1f_bih = (const float*)d_in[5];
    const float* l1f_bhh = (const float*)d_in[6];
    const float* l1b_Wih = (const float*)d_in[7];
    const float* l1b_Whh = (const float*)d_in[8];
    const float* l1b_bih = (const float*)d_in[9];
    const float* l1b_bhh = (const float*)d_in[10];
    const float* l2f_Wih = (const float*)d_in[11];
    const float* l2f_Whh = (const float*)d_in[12];
    const float* l2f_bih = (const float*)d_in[13];
    const float* l2f_bhh = (const float*)d_in[14];
    const float* l2b_Wih = (const float*)d_in[15];
    const float* l2b_Whh = (const float*)d_in[16];
    const float* l2b_bih = (const float*)d_in[17];
    const float* l2b_bhh = (const float*)d_in[18];
    const float* cls_W   = (const float*)d_in[19];
    const float* cls_b   = (const float*)d_in[20];
    (void)in_sizes; (void)n_in; (void)out_size; (void)ws_size;

    char* ws = (char*)d_ws;
    size_t off = 0;
    auto alloc = [&](size_t b) { void* p = ws + off; off += (b + 255) & ~(size_t)255; return p; };
    _Float16*  xg = (_Float16*)alloc((size_t)Mq * 2048 * 2);  // 128 MiB, full width (no phasing)
    _Float16*  o1 = (_Float16*)alloc((size_t)Mq * 512 * 2);   // 32 MiB
    _Float16*  o2 = (_Float16*)alloc((size_t)Mq * 512 * 2);   // 32 MiB
    _Float16* PAk = (_Float16*)alloc((size_t)4 * 262144 * 2); // 2 MiB lstm A-frags
    _Float16* PB1 = (_Float16*)alloc((size_t)2 * 131072 * 2); // 512 KB l1 B-frags (K=128, 2 dirs)
    _Float16* PB2 = (_Float16*)alloc((size_t)2 * 524288 * 2); // 2 MiB l2 B-frags (K=512, 2 dirs)
    _Float16* PBc = (_Float16*)alloc((size_t)131072 * 2);     // 256 KB cls B-frags (Npad=256, K=512)
    float* biasbuf = (float*)alloc((size_t)4 * 1024 * 4);
    unsigned* dflags = (unsigned*)alloc(256);
    // total ~197 MiB

    _Float16* PA1f = PAk;
    _Float16* PA1b = PAk + 262144;
    _Float16* PA2f = PAk + 2 * 262144;
    _Float16* PA2b = PAk + 3 * 262144;

    const size_t ldsBytes = 131072 + 16512 + 4224;   // 151808
    hipFuncSetAttribute((const void*)lstm_mfma, hipFuncAttributeMaxDynamicSharedMemorySize, (int)ldsBytes);

    detect_int64<<<1, 256, 0, stream>>>(words, lens, dflags);
    bias_kernel<<<dim3(16), 256, 0, stream>>>(l1f_bih, l1f_bhh, l1b_bih, l1b_bhh,
                                              l2f_bih, l2f_bhh, l2b_bih, l2b_bhh, biasbuf);
    pack_whh_mfma<<<dim3(128), 256, 0, stream>>>(l1f_Whh, PA1f);
    pack_whh_mfma<<<dim3(128), 256, 0, stream>>>(l1b_Whh, PA1b);
    pack_whh_mfma<<<dim3(128), 256, 0, stream>>>(l2f_Whh, PA2f);
    pack_whh_mfma<<<dim3(128), 256, 0, stream>>>(l2b_Whh, PA2b);
    // B-frag packs: l1 (K=128): 64 ntiles * 4 kc * 64 = 16384 chunks per dir
    pack_w_bfrag<<<dim3(64), 256, 0, stream>>>(l1f_Wih, PB1, 1024, 128, 16384);
    pack_w_bfrag<<<dim3(64), 256, 0, stream>>>(l1b_Wih, PB1 + 131072, 1024, 128, 16384);
    // l2 (K=512): 64 * 16 * 64 = 65536 chunks per dir
    pack_w_bfrag<<<dim3(256), 256, 0, stream>>>(l2f_Wih, PB2, 1024, 512, 65536);
    pack_w_bfrag<<<dim3(256), 256, 0, stream>>>(l2b_Wih, PB2 + 524288, 1024, 512, 65536);
    // cls (Npad=256, K=512): 16 * 16 * 64 = 16384 chunks
    pack_w_bfrag<<<dim3(64), 256, 0, stream>>>(cls_W, PBc, NTAGS, 512, 16384);

    // ---- layer 1: xg = gather(emb) @ [Wih_f || Wih_b]^T + bias ----
    gemm_mfma<2, 1><<<dim3(8, Mq / 64), 256, 0, stream>>>(nullptr, words, emb, dflags,
        PB1, biasbuf, xg, 2048, 128, 2048);
    lstm_mfma<<<32, 1024, ldsBytes, stream>>>(xg, PA1f, PA1b, lens, dflags, o1);
    // ---- layer 2 ----
    gemm_mfma<0, 1><<<dim3(8, Mq / 64), 256, 0, stream>>>(o1, nullptr, nullptr, dflags,
        PB2, biasbuf + 2048, xg, 2048, 512, 2048);
    lstm_mfma<<<32, 1024, ldsBytes, stream>>>(xg, PA2f, PA2b, lens, dflags, o2);
    // ---- classifier -> d_out (f32) ----
    gemm_mfma<0, 0><<<dim3(1, Mq / 64), 256, 0, stream>>>(o2, nullptr, nullptr, dflags,
        PBc, cls_b, d_out, NTAGS, 512, NTAGS);
}